// Round 1
// baseline (1877.175 us; speedup 1.0000x reference)
//
#include <hip/hip_runtime.h>
#include <hip/hip_bf16.h>
#include <cstddef>

// Problem constants
#define NN 16
#define CC 64
#define TT 300
#define VV 25
#define NHH 4
#define DKHH 16
#define BB (NN * VV)          // 400
#define QKVO (2 * 64 + 64)    // 192

// ---------------------------------------------------------------------------
// Kernel 1: data_bn (eval) fused into 1x1 qkv conv.
// One thread per (b, t) column. xa column (64 ch) in registers.
// qkv_w / qkv_b accesses are thread-uniform -> scalar loads.
// Output layout: qkv[b][o][t], t contiguous (coalesced stores).
// ---------------------------------------------------------------------------
__global__ __launch_bounds__(128) void k_qkv(
        const float* __restrict__ x,
        const float* __restrict__ dbn_g, const float* __restrict__ dbn_b,
        const float* __restrict__ dbn_m, const float* __restrict__ dbn_v,
        const float* __restrict__ qkv_w, const float* __restrict__ qkv_b,
        float* __restrict__ qkvo)
{
    const int b = blockIdx.x;              // 0..399
    const int n = b / VV;
    const int v = b - n * VV;
    const int t = blockIdx.y * 128 + threadIdx.x;
    if (t >= TT) return;

    float a[CC];
    #pragma unroll
    for (int c = 0; c < CC; ++c) {
        const int ch = c * VV + v;
        const float sc = dbn_g[ch] * rsqrtf(dbn_v[ch] + 1e-5f);
        const float sh = dbn_b[ch] - dbn_m[ch] * sc;
        a[c] = x[((size_t)(n * CC + c) * TT + t) * VV + v] * sc + sh;
    }

    float* outp = qkvo + (size_t)b * QKVO * TT + t;
    #pragma unroll 2
    for (int o = 0; o < QKVO; ++o) {
        float a0 = 0.f, a1 = 0.f, a2 = 0.f, a3 = 0.f;
        #pragma unroll
        for (int c = 0; c < CC; c += 4) {
            a0 = fmaf(qkv_w[o * CC + c + 0], a[c + 0], a0);
            a1 = fmaf(qkv_w[o * CC + c + 1], a[c + 1], a1);
            a2 = fmaf(qkv_w[o * CC + c + 2], a[c + 2], a2);
            a3 = fmaf(qkv_w[o * CC + c + 3], a[c + 3], a3);
        }
        outp[(size_t)o * TT] = ((a0 + a1) + (a2 + a3)) + qkv_b[o];
    }
}

// ---------------------------------------------------------------------------
// Kernel 2: relative-position attention per (b, h). 1600 blocks x 512 thr.
// LDS: K,V tiles [d][t] + per-wave p row. 48 KB -> 3 blocks/CU.
// Each wave owns rows t = wave + 8k (no intra-loop barriers; sp is
// per-wave private and same-wave LDS ops are in-order).
// logits[t][s] = q[t].k[s] + q[t].key_rel[s - t + T - 1]
// ---------------------------------------------------------------------------
__global__ __launch_bounds__(512) void k_attn(
        const float* __restrict__ qkv, const float* __restrict__ key_rel,
        float* __restrict__ attnh)
{
    const int bh = blockIdx.x;             // 0..1599
    const int b = bh >> 2, h = bh & 3;
    const int tid = threadIdx.x;
    const int wave = tid >> 6, lane = tid & 63;

    __shared__ float sk[DKHH * TT];        // 19.2 KB
    __shared__ float sv[DKHH * TT];        // 19.2 KB
    __shared__ float sp[8][TT];            //  9.6 KB

    const float* base = qkv + ((size_t)b * QKVO + h * DKHH) * TT;
    for (int i = tid; i < DKHH * TT; i += 512) {
        sk[i] = base[64 * TT + i];
        sv[i] = base[128 * TT + i];
    }
    __syncthreads();

    const int d16 = lane & 15, sg = lane >> 4;
    const float* qptr_base = qkv + ((size_t)b * QKVO + h * DKHH) * TT;

    for (int t = wave; t < TT; t += 8) {
        // q row (broadcast loads, 16x 64B lines from L1/L2)
        float qrow[DKHH];
        #pragma unroll
        for (int d = 0; d < DKHH; ++d)
            qrow[d] = qptr_base[(size_t)d * TT + t] * 0.25f;

        // ---- logits: lane covers s = 4*lane + 256*j .. +3 ----
        float lg[8];
        #pragma unroll
        for (int j = 0; j < 2; ++j) {
            const int s0 = 256 * j + 4 * lane;
            if (s0 < TT) {
                float4 acc4 = make_float4(0.f, 0.f, 0.f, 0.f);
                #pragma unroll
                for (int d = 0; d < DKHH; ++d) {
                    const float4 k4 = *(const float4*)&sk[d * TT + s0];
                    acc4.x = fmaf(qrow[d], k4.x, acc4.x);
                    acc4.y = fmaf(qrow[d], k4.y, acc4.y);
                    acc4.z = fmaf(qrow[d], k4.z, acc4.z);
                    acc4.w = fmaf(qrow[d], k4.w, acc4.w);
                }
                // rel term from global (rows are 64B aligned)
                const float* kr = key_rel + (size_t)(s0 - t + TT - 1) * DKHH;
                float rr[4];
                #pragma unroll
                for (int r = 0; r < 4; ++r) {
                    float ar = 0.f;
                    #pragma unroll
                    for (int d4 = 0; d4 < 4; ++d4) {
                        const float4 k4 = *(const float4*)&kr[r * DKHH + d4 * 4];
                        ar = fmaf(qrow[d4 * 4 + 0], k4.x, ar);
                        ar = fmaf(qrow[d4 * 4 + 1], k4.y, ar);
                        ar = fmaf(qrow[d4 * 4 + 2], k4.z, ar);
                        ar = fmaf(qrow[d4 * 4 + 3], k4.w, ar);
                    }
                    rr[r] = ar;
                }
                lg[4 * j + 0] = acc4.x + rr[0];
                lg[4 * j + 1] = acc4.y + rr[1];
                lg[4 * j + 2] = acc4.z + rr[2];
                lg[4 * j + 3] = acc4.w + rr[3];
            } else {
                lg[4 * j + 0] = -1e30f; lg[4 * j + 1] = -1e30f;
                lg[4 * j + 2] = -1e30f; lg[4 * j + 3] = -1e30f;
            }
        }

        // ---- softmax (wave butterfly) ----
        float mx = lg[0];
        #pragma unroll
        for (int i = 1; i < 8; ++i) mx = fmaxf(mx, lg[i]);
        mx = fmaxf(mx, __shfl_xor(mx, 32, 64));
        mx = fmaxf(mx, __shfl_xor(mx, 16, 64));
        mx = fmaxf(mx, __shfl_xor(mx, 8, 64));
        mx = fmaxf(mx, __shfl_xor(mx, 4, 64));
        mx = fmaxf(mx, __shfl_xor(mx, 2, 64));
        mx = fmaxf(mx, __shfl_xor(mx, 1, 64));

        float p[8];
        float sum = 0.f;
        #pragma unroll
        for (int i = 0; i < 8; ++i) {
            p[i] = __expf(lg[i] - mx);     // -1e30 -> exp underflows to 0
            sum += p[i];
        }
        sum += __shfl_xor(sum, 32, 64);
        sum += __shfl_xor(sum, 16, 64);
        sum += __shfl_xor(sum, 8, 64);
        sum += __shfl_xor(sum, 4, 64);
        sum += __shfl_xor(sum, 2, 64);
        sum += __shfl_xor(sum, 1, 64);
        const float inv = 1.f / sum;       // same in all lanes

        // stash unnormalized p row (per-wave private)
        #pragma unroll
        for (int j = 0; j < 2; ++j) {
            const int s0 = 256 * j + 4 * lane;
            if (s0 < TT)
                *(float4*)&sp[wave][s0] =
                    make_float4(p[4 * j], p[4 * j + 1], p[4 * j + 2], p[4 * j + 3]);
        }

        // ---- PV: lane = (sg, d16) ----
        float acc = 0.f;
        #pragma unroll
        for (int k = 0; k < 19; ++k) {
            const int s0 = 16 * k + 4 * sg;
            if (s0 < TT) {
                const float4 p4 = *(const float4*)&sp[wave][s0];
                const float4 v4 = *(const float4*)&sv[d16 * TT + s0];
                acc = fmaf(p4.x, v4.x, acc);
                acc = fmaf(p4.y, v4.y, acc);
                acc = fmaf(p4.z, v4.z, acc);
                acc = fmaf(p4.w, v4.w, acc);
            }
        }
        acc += __shfl_xor(acc, 16, 64);
        acc += __shfl_xor(acc, 32, 64);
        if (sg == 0)
            attnh[((size_t)b * 64 + h * DKHH + d16) * TT + t] = acc * inv;
    }
}

// ---------------------------------------------------------------------------
// Kernel 3: output projection + skip + BN(eval) + ReLU.
// One thread per (b, t) column; attn_w / biases / bn params uniform -> s_load.
// ---------------------------------------------------------------------------
__global__ __launch_bounds__(128) void k_out(
        const float* __restrict__ attnh, const float* __restrict__ attn_w,
        const float* __restrict__ attn_b, const float* __restrict__ x,
        const float* __restrict__ bn_g, const float* __restrict__ bn_b,
        const float* __restrict__ bn_m, const float* __restrict__ bn_v,
        float* __restrict__ out)
{
    const int b = blockIdx.x;              // 0..399
    const int n = b / VV;
    const int v = b - n * VV;
    const int t = blockIdx.y * 128 + threadIdx.x;
    if (t >= TT) return;

    float a[64];
    #pragma unroll
    for (int c = 0; c < 64; ++c)
        a[c] = attnh[((size_t)b * 64 + c) * TT + t];

    #pragma unroll 2
    for (int o = 0; o < 64; ++o) {
        float a0 = 0.f, a1 = 0.f, a2 = 0.f, a3 = 0.f;
        #pragma unroll
        for (int c = 0; c < 64; c += 4) {
            a0 = fmaf(attn_w[o * 64 + c + 0], a[c + 0], a0);
            a1 = fmaf(attn_w[o * 64 + c + 1], a[c + 1], a1);
            a2 = fmaf(attn_w[o * 64 + c + 2], a[c + 2], a2);
            a3 = fmaf(attn_w[o * 64 + c + 3], a[c + 3], a3);
        }
        float val = ((a0 + a1) + (a2 + a3)) + attn_b[o];
        const size_t xi = ((size_t)(n * 64 + o) * TT + t) * VV + v;
        float res = val + x[xi];
        const float sc = bn_g[o] * rsqrtf(bn_v[o] + 1e-5f);
        const float sh = bn_b[o] - bn_m[o] * sc;
        res = fmaf(res, sc, sh);
        out[xi] = fmaxf(res, 0.f);
    }
}

// ---------------------------------------------------------------------------
extern "C" void kernel_launch(void* const* d_in, const int* in_sizes, int n_in,
                              void* d_out, int out_size, void* d_ws, size_t ws_size,
                              hipStream_t stream)
{
    const float* x       = (const float*)d_in[0];
    const float* dbn_g   = (const float*)d_in[1];
    const float* dbn_b   = (const float*)d_in[2];
    const float* dbn_m   = (const float*)d_in[3];
    const float* dbn_v   = (const float*)d_in[4];
    const float* qkv_w   = (const float*)d_in[5];
    const float* qkv_b   = (const float*)d_in[6];
    const float* key_rel = (const float*)d_in[7];
    const float* attn_w  = (const float*)d_in[8];
    const float* attn_b  = (const float*)d_in[9];
    const float* bn_g    = (const float*)d_in[10];
    const float* bn_b    = (const float*)d_in[11];
    const float* bn_m    = (const float*)d_in[12];
    const float* bn_v    = (const float*)d_in[13];
    float* out = (float*)d_out;

    // workspace: qkv (400*192*300 = 23.04M f) + attnh (400*64*300 = 7.68M f)
    float* qkv   = (float*)d_ws;
    float* attnh = qkv + (size_t)BB * QKVO * TT;

    k_qkv<<<dim3(BB, 3), 128, 0, stream>>>(x, dbn_g, dbn_b, dbn_m, dbn_v,
                                           qkv_w, qkv_b, qkv);
    k_attn<<<dim3(BB * NHH), 512, 0, stream>>>(qkv, key_rel, attnh);
    k_out<<<dim3(BB, 3), 128, 0, stream>>>(attnh, attn_w, attn_b, x,
                                           bn_g, bn_b, bn_m, bn_v, out);
}

// Round 2
// 621.785 us; speedup vs baseline: 3.0190x; 3.0190x over previous
//
#include <hip/hip_runtime.h>
#include <hip/hip_bf16.h>
#include <cstddef>

// Problem constants
#define NN 16
#define CC 64
#define TT 300
#define VV 25
#define NHH 4
#define DKHH 16
#define BB (NN * VV)          // 400
#define QKVO (2 * 64 + 64)    // 192

typedef __attribute__((ext_vector_type(8))) short short8;
typedef __attribute__((ext_vector_type(4))) float float4v;

union U8 { short8 v; unsigned int w[4]; };

// round-to-nearest-even f32 -> bf16, two at a time, packed into u32
__device__ __forceinline__ unsigned int packbf2(float a, float b) {
    union { float f; unsigned u; } x, y;
    x.f = a; y.f = b;
    unsigned ua = x.u + 0x7FFFu + ((x.u >> 16) & 1u);
    unsigned ub = y.u + 0x7FFFu + ((y.u >> 16) & 1u);
    return (ua >> 16) | (ub & 0xFFFF0000u);
}

// ---------------------------------------------------------------------------
// Kernel 1: data_bn (eval) fused into 1x1 qkv conv.  (unchanged from R1)
// ---------------------------------------------------------------------------
__global__ __launch_bounds__(128) void k_qkv(
        const float* __restrict__ x,
        const float* __restrict__ dbn_g, const float* __restrict__ dbn_b,
        const float* __restrict__ dbn_m, const float* __restrict__ dbn_v,
        const float* __restrict__ qkv_w, const float* __restrict__ qkv_b,
        float* __restrict__ qkvo)
{
    const int b = blockIdx.x;              // 0..399
    const int n = b / VV;
    const int v = b - n * VV;
    const int t = blockIdx.y * 128 + threadIdx.x;
    if (t >= TT) return;

    float a[CC];
    #pragma unroll
    for (int c = 0; c < CC; ++c) {
        const int ch = c * VV + v;
        const float sc = dbn_g[ch] * rsqrtf(dbn_v[ch] + 1e-5f);
        const float sh = dbn_b[ch] - dbn_m[ch] * sc;
        a[c] = x[((size_t)(n * CC + c) * TT + t) * VV + v] * sc + sh;
    }

    float* outp = qkvo + (size_t)b * QKVO * TT + t;
    #pragma unroll 2
    for (int o = 0; o < QKVO; ++o) {
        float a0 = 0.f, a1 = 0.f, a2 = 0.f, a3 = 0.f;
        #pragma unroll
        for (int c = 0; c < CC; c += 4) {
            a0 = fmaf(qkv_w[o * CC + c + 0], a[c + 0], a0);
            a1 = fmaf(qkv_w[o * CC + c + 1], a[c + 1], a1);
            a2 = fmaf(qkv_w[o * CC + c + 2], a[c + 2], a2);
            a3 = fmaf(qkv_w[o * CC + c + 3], a[c + 3], a3);
        }
        outp[(size_t)o * TT] = ((a0 + a1) + (a2 + a3)) + qkv_b[o];
    }
}

// ---------------------------------------------------------------------------
// Kernel 2 (MFMA rewrite): relative-position attention per (b, h).
// 1600 blocks x 256 threads (4 waves). Each wave owns t-tiles tt=wave+4k.
// All GEMM-shaped work on mfma_f32_16x16x32_bf16:
//   - QK^T  : A=Q(16t x 32k, d zero-padded), B=K^T     -> C-layout logits
//   - rel   : A=Q,                    B=key_rel^T       -> ring buffer in LDS
//   - PV    : A=P (packed in regs after C->A transpose), B=V (K=32 real)
// No max-subtraction (logits bounded ~|4|); plain sum + final divide.
// No barriers after the one staging __syncthreads().
// ---------------------------------------------------------------------------
__global__ __launch_bounds__(256) void k_attn(
        const float* __restrict__ qkv, const float* __restrict__ key_rel,
        float* __restrict__ attnh)
{
    const int bh = blockIdx.x;             // 0..1599
    const int b = bh >> 2, h = bh & 3;
    const int tid  = threadIdx.x;
    const int wave = tid >> 6, lane = tid & 63;
    const int col  = lane & 15, quad = lane >> 4;

    // LDS
    __shared__ unsigned int kbuf[20 * 32 * 4];   // K B-frags (quads 0,1), 10 KB
    __shared__ unsigned int vbuf[10 * 64 * 4];   // V B-frags, 10 KB
    __shared__ float relbuf[4][16 * 67];         // rel ring, stride 67, 17.2 KB
    __shared__ float tbuf[4][16 * 33];           // logits transpose, 8.4 KB
    __shared__ float sbuf[4][16];                // row sums

    const float* qbase = qkv + ((size_t)b * QKVO +       h * DKHH) * TT;
    const float* kbase = qkv + ((size_t)b * QKVO +  64 + h * DKHH) * TT;
    const float* vbase = qkv + ((size_t)b * QKVO + 128 + h * DKHH) * TT;

    // ---- stage K: element (st, qh, c, j) = K[d=qh*8+j][s=st*16+c] ----
    for (int p = tid; p < 2560; p += 256) {
        const int j2 = p & 3, c = (p >> 2) & 15, qh = (p >> 6) & 1, st = p >> 7;
        const int d = qh * 8 + 2 * j2, s = st * 16 + c;
        const float v0 = (s < TT) ? kbase[(size_t)d * TT + s] : 0.f;
        const float v1 = (s < TT) ? kbase[(size_t)(d + 1) * TT + s] : 0.f;
        kbuf[(st * 32 + qh * 16 + c) * 4 + j2] = packbf2(v0, v1);
    }
    // ---- stage V: element (sp, q4, c, j) = V[s=sp*32+q4*8+j][d=c] ----
    for (int p = tid; p < 2560; p += 256) {
        const int j2 = p & 3, c = (p >> 2) & 15, q4 = (p >> 6) & 3, sp = p >> 8;
        const int s = sp * 32 + q4 * 8 + 2 * j2;
        const float v0 = (s < TT)     ? vbase[(size_t)c * TT + s]     : 0.f;
        const float v1 = (s + 1 < TT) ? vbase[(size_t)c * TT + s + 1] : 0.f;
        vbuf[(sp * 64 + q4 * 16 + c) * 4 + j2] = packbf2(v0, v1);
    }
    __syncthreads();

    float* relw = &relbuf[wave][0];
    float* tw   = &tbuf[wave][0];
    const float4v zero4 = {0.f, 0.f, 0.f, 0.f};

    for (int tt = wave; tt < 19; tt += 4) {
        const int t0 = tt * 16;

        // ---- Q A-frag from global: A[row=col][k=quad*8+j] = q[d=k][t0+row]
        U8 qf;
        if (quad < 2) {
            int t = t0 + col; if (t > TT - 1) t = TT - 1;
            const float* qp = qbase + (size_t)(quad * 8) * TT + t;
            #pragma unroll
            for (int j2 = 0; j2 < 4; ++j2)
                qf.w[j2] = packbf2(qp[(size_t)(2 * j2) * TT] * 0.25f,
                                   qp[(size_t)(2 * j2 + 1) * TT] * 0.25f);
        } else {
            qf.w[0] = qf.w[1] = qf.w[2] = qf.w[3] = 0u;
        }

        // ---- prologue: rel tiles (17-tt), (18-tt) into the ring ----
        #pragma unroll
        for (int i = 0; i < 2; ++i) {
            const int mt = 17 - tt + i;
            U8 kr;
            const int m = mt * 16 + col;
            if (quad < 2 && m >= 0 && m < 2 * TT - 1) {
                const float* rp = key_rel + (size_t)m * DKHH + quad * 8;
                const float4 a = *(const float4*)rp;
                const float4 bb = *(const float4*)(rp + 4);
                kr.w[0] = packbf2(a.x, a.y);  kr.w[1] = packbf2(a.z, a.w);
                kr.w[2] = packbf2(bb.x, bb.y); kr.w[3] = packbf2(bb.z, bb.w);
            } else { kr.w[0] = kr.w[1] = kr.w[2] = kr.w[3] = 0u; }
            const float4v rc = __builtin_amdgcn_mfma_f32_16x16x32_bf16(
                                   qf.v, kr.v, zero4, 0, 0, 0);
            const int slot = ((mt & 3) * 16 + col);
            #pragma unroll
            for (int r = 0; r < 4; ++r)
                relw[(4 * quad + r) * 67 + slot] = rc[r];
        }

        float4v accPV = zero4;
        float  sumA = 0.f;

        #pragma unroll 1
        for (int c = 0; c < 10; ++c) {
            const int mt_lo = 2 * c - tt + 17;

            // ---- 2 new rel tiles per chunk ----
            #pragma unroll
            for (int i = 2; i < 4; ++i) {
                const int mt = mt_lo + i;
                U8 kr;
                const int m = mt * 16 + col;
                if (quad < 2 && m >= 0 && m < 2 * TT - 1) {
                    const float* rp = key_rel + (size_t)m * DKHH + quad * 8;
                    const float4 a = *(const float4*)rp;
                    const float4 bb = *(const float4*)(rp + 4);
                    kr.w[0] = packbf2(a.x, a.y);  kr.w[1] = packbf2(a.z, a.w);
                    kr.w[2] = packbf2(bb.x, bb.y); kr.w[3] = packbf2(bb.z, bb.w);
                } else { kr.w[0] = kr.w[1] = kr.w[2] = kr.w[3] = 0u; }
                const float4v rc = __builtin_amdgcn_mfma_f32_16x16x32_bf16(
                                       qf.v, kr.v, zero4, 0, 0, 0);
                const int slot = ((mt & 3) * 16 + col);
                #pragma unroll
                for (int r = 0; r < 4; ++r)
                    relw[(4 * quad + r) * 67 + slot] = rc[r];
            }

            // ---- QK for the two s-tiles of this chunk ----
            float4v qk[2];
            #pragma unroll
            for (int sti = 0; sti < 2; ++sti) {
                const int st = 2 * c + sti;
                short8 kf;
                if (quad < 2) {
                    kf = *(const short8*)&kbuf[(st * 32 + quad * 16 + col) * 4];
                } else {
                    U8 z; z.w[0] = z.w[1] = z.w[2] = z.w[3] = 0u; kf = z.v;
                }
                qk[sti] = __builtin_amdgcn_mfma_f32_16x16x32_bf16(
                              qf.v, kf, zero4, 0, 0, 0);
            }

            // ---- C-layout epilogue: add rel (ring gather), park in tbuf ----
            #pragma unroll
            for (int sti = 0; sti < 2; ++sti) {
                const int s = (2 * c + sti) * 16 + col;
                #pragma unroll
                for (int r = 0; r < 4; ++r) {
                    const int row = 4 * quad + r;
                    const int m = s - (t0 + row) + (TT - 1);
                    const float rel =
                        relw[row * 67 + ((m >> 4) & 3) * 16 + (m & 15)];
                    tw[row * 33 + sti * 16 + col] = qk[sti][r] + rel;
                }
            }

            // ---- A-layout: exp, row-sum partial, pack P frag in regs ----
            const int ka = quad * 8;          // within-chunk s offset
            U8 pf;
            #pragma unroll
            for (int j2 = 0; j2 < 4; ++j2) {
                float p0 = tw[col * 33 + ka + 2 * j2];
                float p1 = tw[col * 33 + ka + 2 * j2 + 1];
                p0 = (32 * c + ka + 2 * j2     < TT) ? __expf(p0) : 0.f;
                p1 = (32 * c + ka + 2 * j2 + 1 < TT) ? __expf(p1) : 0.f;
                sumA += p0 + p1;
                pf.w[j2] = packbf2(p0, p1);
            }
            const short8 vf = *(const short8*)&vbuf[(c * 64 + lane) * 4];
            accPV = __builtin_amdgcn_mfma_f32_16x16x32_bf16(
                        pf.v, vf, accPV, 0, 0, 0);
        }

        // ---- finalize tile: row sums, normalize, store ----
        sumA += __shfl_xor(sumA, 16, 64);
        sumA += __shfl_xor(sumA, 32, 64);
        if (lane < 16) sbuf[wave][lane] = sumA;
        const float4 rs = *(const float4*)&sbuf[wave][4 * quad];
        const float rsum[4] = {rs.x, rs.y, rs.z, rs.w};
        #pragma unroll
        for (int r = 0; r < 4; ++r) {
            const int t = t0 + 4 * quad + r;
            if (t < TT)
                attnh[((size_t)b * 64 + h * DKHH + col) * TT + t] =
                    accPV[r] / rsum[r];
        }
    }
}

// ---------------------------------------------------------------------------
// Kernel 3: output projection + skip + BN(eval) + ReLU.  (unchanged from R1)
// ---------------------------------------------------------------------------
__global__ __launch_bounds__(128) void k_out(
        const float* __restrict__ attnh, const float* __restrict__ attn_w,
        const float* __restrict__ attn_b, const float* __restrict__ x,
        const float* __restrict__ bn_g, const float* __restrict__ bn_b,
        const float* __restrict__ bn_m, const float* __restrict__ bn_v,
        float* __restrict__ out)
{
    const int b = blockIdx.x;              // 0..399
    const int n = b / VV;
    const int v = b - n * VV;
    const int t = blockIdx.y * 128 + threadIdx.x;
    if (t >= TT) return;

    float a[64];
    #pragma unroll
    for (int c = 0; c < 64; ++c)
        a[c] = attnh[((size_t)b * 64 + c) * TT + t];

    #pragma unroll 2
    for (int o = 0; o < 64; ++o) {
        float a0 = 0.f, a1 = 0.f, a2 = 0.f, a3 = 0.f;
        #pragma unroll
        for (int c = 0; c < 64; c += 4) {
            a0 = fmaf(attn_w[o * 64 + c + 0], a[c + 0], a0);
            a1 = fmaf(attn_w[o * 64 + c + 1], a[c + 1], a1);
            a2 = fmaf(attn_w[o * 64 + c + 2], a[c + 2], a2);
            a3 = fmaf(attn_w[o * 64 + c + 3], a[c + 3], a3);
        }
        float val = ((a0 + a1) + (a2 + a3)) + attn_b[o];
        const size_t xi = ((size_t)(n * 64 + o) * TT + t) * VV + v;
        float res = val + x[xi];
        const float sc = bn_g[o] * rsqrtf(bn_v[o] + 1e-5f);
        const float sh = bn_b[o] - bn_m[o] * sc;
        res = fmaf(res, sc, sh);
        out[xi] = fmaxf(res, 0.f);
    }
}

// ---------------------------------------------------------------------------
extern "C" void kernel_launch(void* const* d_in, const int* in_sizes, int n_in,
                              void* d_out, int out_size, void* d_ws, size_t ws_size,
                              hipStream_t stream)
{
    const float* x       = (const float*)d_in[0];
    const float* dbn_g   = (const float*)d_in[1];
    const float* dbn_b   = (const float*)d_in[2];
    const float* dbn_m   = (const float*)d_in[3];
    const float* dbn_v   = (const float*)d_in[4];
    const float* qkv_w   = (const float*)d_in[5];
    const float* qkv_b   = (const float*)d_in[6];
    const float* key_rel = (const float*)d_in[7];
    const float* attn_w  = (const float*)d_in[8];
    const float* attn_b  = (const float*)d_in[9];
    const float* bn_g    = (const float*)d_in[10];
    const float* bn_b    = (const float*)d_in[11];
    const float* bn_m    = (const float*)d_in[12];
    const float* bn_v    = (const float*)d_in[13];
    float* out = (float*)d_out;

    // workspace: qkv (400*192*300 = 23.04M f) + attnh (400*64*300 = 7.68M f)
    float* qkv   = (float*)d_ws;
    float* attnh = qkv + (size_t)BB * QKVO * TT;

    k_qkv<<<dim3(BB, 3), 128, 0, stream>>>(x, dbn_g, dbn_b, dbn_m, dbn_v,
                                           qkv_w, qkv_b, qkv);
    k_attn<<<dim3(BB * NHH), 256, 0, stream>>>(qkv, key_rel, attnh);
    k_out<<<dim3(BB, 3), 128, 0, stream>>>(attnh, attn_w, attn_b, x,
                                           bn_g, bn_b, bn_m, bn_v, out);
}

// Round 3
// 341.369 us; speedup vs baseline: 5.4990x; 1.8214x over previous
//
#include <hip/hip_runtime.h>
#include <hip/hip_bf16.h>
#include <cstddef>

// Problem constants
#define NN 16
#define CC 64
#define TT 300
#define VV 25
#define NHH 4
#define DKHH 16
#define BB (NN * VV)          // 400
#define EPS 1e-5f

// Workspace layout (u32 units)
#define WS_QK    0            // u32[400][64][300]  q|k bf16, paired along o
#define WS_V     7680000      // u32[400][64][152]  v bf16, paired along t
#define WS_AH    11571200     // u32[400][64][152]  attnh bf16, paired along t
#define WS_SCSH  15462400     // float2[1600] data_bn (sc, sh) per (c, v)
#define WS_WFRAG 15465600     // u32[12][2][64][4] qkv_w B-frags (q rows pre-scaled 0.25)
#define WS_QB2   15471744     // f32[192] qkv_b (q pre-scaled 0.25)
#define WS_AWF   15471936     // u32[4][2][64][4] attn_w B-frags (pre-scaled by bn scale)
#define WS_AOFF  15473984     // f32[64] fused attn_b+bn offset
#define WS_SCO   15474048     // f32[64] bn scale (for skip path)
#define WS_REL   15474112     // u32[41][64][4] key_rel B-frags (slot = mtile+1, slot0 = zeros)

typedef __attribute__((ext_vector_type(8))) short short8;
typedef __attribute__((ext_vector_type(4))) float float4v;

union U8 { short8 v; unsigned int w[4]; };

// round-to-nearest-even f32 -> bf16, two at a time, packed into u32 (lo = a)
__device__ __forceinline__ unsigned int packbf2(float a, float b) {
    union { float f; unsigned u; } x, y;
    x.f = a; y.f = b;
    unsigned ua = x.u + 0x7FFFu + ((x.u >> 16) & 1u);
    unsigned ub = y.u + 0x7FFFu + ((y.u >> 16) & 1u);
    return (ua >> 16) | (ub & 0xFFFF0000u);
}

// ---------------------------------------------------------------------------
// k_pre: build all constant tables (weight fragments, bn coefficients,
// key_rel fragments). 6592 lane-jobs, trivial runtime.
// ---------------------------------------------------------------------------
__global__ __launch_bounds__(256) void k_pre(
    const float* __restrict__ dbn_g, const float* __restrict__ dbn_b,
    const float* __restrict__ dbn_m, const float* __restrict__ dbn_v,
    const float* __restrict__ qkv_w, const float* __restrict__ qkv_b,
    const float* __restrict__ key_rel,
    const float* __restrict__ attn_w, const float* __restrict__ attn_b,
    const float* __restrict__ bn_g, const float* __restrict__ bn_b,
    const float* __restrict__ bn_m, const float* __restrict__ bn_v,
    unsigned* __restrict__ W)
{
    const int jid = blockIdx.x * 256 + threadIdx.x;
    if (jid < 2624) {                      // relfrag: 41 slots x 64 lanes
        const int k = jid >> 6, lane = jid & 63, col = lane & 15, quad = lane >> 4;
        const int mt = k - 1, m = mt * 16 + col;
        const bool ok = (quad < 2) && (mt >= 0) && (m < 2 * TT - 1);
        unsigned w[4];
        #pragma unroll
        for (int j2 = 0; j2 < 4; ++j2) {
            const int c = quad * 8 + 2 * j2;
            const float v0 = ok ? key_rel[m * 16 + c] : 0.f;
            const float v1 = ok ? key_rel[m * 16 + c + 1] : 0.f;
            w[j2] = packbf2(v0, v1);
        }
        *(uint4*)&W[WS_REL + k * 256 + lane * 4] = make_uint4(w[0], w[1], w[2], w[3]);
    } else if (jid < 4160) {               // wfrag: 12 otiles x 2 chalf x 64
        const int e = jid - 2624;
        const int ot = e >> 7, ch = (e >> 6) & 1, lane = e & 63;
        const int col = lane & 15, quad = lane >> 4;
        const int o = ot * 16 + col;
        const float s = (o < 64) ? 0.25f : 1.f;
        unsigned w[4];
        #pragma unroll
        for (int j2 = 0; j2 < 4; ++j2) {
            const int c = ch * 32 + quad * 8 + 2 * j2;
            w[j2] = packbf2(qkv_w[o * 64 + c] * s, qkv_w[o * 64 + c + 1] * s);
        }
        *(uint4*)&W[WS_WFRAG + (ot * 2 + ch) * 256 + lane * 4] = make_uint4(w[0], w[1], w[2], w[3]);
    } else if (jid < 4672) {               // awfrag: 4 otiles x 2 chalf x 64
        const int e = jid - 4160;
        const int ot = e >> 7, ch = (e >> 6) & 1, lane = e & 63;
        const int col = lane & 15, quad = lane >> 4;
        const int o = ot * 16 + col;
        const float sc = bn_g[o] * rsqrtf(bn_v[o] + EPS);
        unsigned w[4];
        #pragma unroll
        for (int j2 = 0; j2 < 4; ++j2) {
            const int c = ch * 32 + quad * 8 + 2 * j2;
            w[j2] = packbf2(attn_w[o * 64 + c] * sc, attn_w[o * 64 + c + 1] * sc);
        }
        *(uint4*)&W[WS_AWF + (ot * 2 + ch) * 256 + lane * 4] = make_uint4(w[0], w[1], w[2], w[3]);
    } else if (jid < 4864) {               // qb2
        const int o = jid - 4672;
        ((float*)(W + WS_QB2))[o] = qkv_b[o] * ((o < 64) ? 0.25f : 1.f);
    } else if (jid < 4928) {               // aoff
        const int o = jid - 4864;
        const float sc = bn_g[o] * rsqrtf(bn_v[o] + EPS);
        ((float*)(W + WS_AOFF))[o] = attn_b[o] * sc + bn_b[o] - bn_m[o] * sc;
    } else if (jid < 4992) {               // scO
        const int o = jid - 4928;
        ((float*)(W + WS_SCO))[o] = bn_g[o] * rsqrtf(bn_v[o] + EPS);
    } else if (jid < 6592) {               // data_bn sc/sh per (c*25+v)
        const int e = jid - 4992;
        const float sc = dbn_g[e] * rsqrtf(dbn_v[e] + EPS);
        const float sh = dbn_b[e] - dbn_m[e] * sc;
        ((float2*)(W + WS_SCSH))[e] = make_float2(sc, sh);
    }
}

// ---------------------------------------------------------------------------
// k_qkv (MFMA): per (t-tile, n). Stage bn(x) as bf16 A-frags in LDS
// (coalesced x reads), MFMA against precomputed weight B-frags, write qkv
// bf16: q|k paired along o (shfl-pack), v paired along t (self-pack).
// ---------------------------------------------------------------------------
__global__ __launch_bounds__(256) void k_qkv(
        const float* __restrict__ x, unsigned* __restrict__ W)
{
    const int tt = blockIdx.x, n = blockIdx.y, t0 = tt * 16;
    const int tid = threadIdx.x;
    const float2* scsh = (const float2*)(W + WS_SCSH);
    const unsigned* wfrag = W + WS_WFRAG;
    const float* qb2 = (const float*)(W + WS_QB2);
    unsigned* qk_p = W + WS_QK;
    unsigned* v_p  = W + WS_V;

    __shared__ unsigned afrag[12896];      // v-stride 516 (4v+4t+j2 banks)

    // stage: 12800 jobs = 25 v x 32 c-pairs x 16 t, (t,v)-flat fastest (coalesced)
    for (int i = tid; i < 12800; i += 256) {
        const int v = i % 25, rest = i / 25;
        const int tcol = rest & 15, pc = rest >> 4;
        const int ch = pc >> 4, quad = (pc >> 2) & 3, j2 = pc & 3;
        const int c0 = pc * 2;
        const int t = t0 + tcol;
        float a0 = 0.f, a1 = 0.f;
        if (t < TT) {
            const size_t base = ((size_t)(n * 64 + c0) * TT + t) * 25 + v;
            const float2 s0 = scsh[c0 * 25 + v];
            const float2 s1 = scsh[c0 * 25 + 25 + v];
            a0 = fmaf(x[base], s0.x, s0.y);
            a1 = fmaf(x[base + 7500], s1.x, s1.y);
        }
        afrag[v * 516 + (ch * 64 + quad * 16 + tcol) * 4 + j2] = packbf2(a0, a1);
    }
    __syncthreads();

    const int wv = tid >> 6, lane = tid & 63, col = lane & 15, quad = lane >> 4;
    const float4v zero4 = {0.f, 0.f, 0.f, 0.f};

    U8 bf[3][2]; float qb_l[3];
    #pragma unroll
    for (int i = 0; i < 3; ++i) {
        const int ot = 3 * wv + i;
        #pragma unroll
        for (int ch = 0; ch < 2; ++ch) {
            const uint4 u = *(const uint4*)&wfrag[(ot * 2 + ch) * 256 + lane * 4];
            bf[i][ch].w[0] = u.x; bf[i][ch].w[1] = u.y; bf[i][ch].w[2] = u.z; bf[i][ch].w[3] = u.w;
        }
        qb_l[i] = qb2[ot * 16 + col];
    }
    const bool tvalid = (t0 + 4 * quad + 3 < TT);   // skip only tile18/quad3

    for (int v = 0; v < 25; ++v) {
        const int b = n * 25 + v;
        U8 a0, a1;
        { const uint4 u = *(const uint4*)&afrag[v * 516 + lane * 4];
          a0.w[0] = u.x; a0.w[1] = u.y; a0.w[2] = u.z; a0.w[3] = u.w; }
        { const uint4 u = *(const uint4*)&afrag[v * 516 + 256 + lane * 4];
          a1.w[0] = u.x; a1.w[1] = u.y; a1.w[2] = u.z; a1.w[3] = u.w; }
        #pragma unroll
        for (int i = 0; i < 3; ++i) {
            const int ot = 3 * wv + i;
            float4v acc = __builtin_amdgcn_mfma_f32_16x16x32_bf16(a0.v, bf[i][0].v, zero4, 0, 0, 0);
            acc = __builtin_amdgcn_mfma_f32_16x16x32_bf16(a1.v, bf[i][1].v, acc, 0, 0, 0);
            float val[4];
            #pragma unroll
            for (int r = 0; r < 4; ++r) val[r] = acc[r] + qb_l[i];
            if (ot < 8) {                  // q|k: pair neighbor o lanes
                unsigned pk[4];
                #pragma unroll
                for (int r = 0; r < 4; ++r) {
                    const float p = __shfl_xor(val[r], 1);
                    pk[r] = packbf2(val[r], p);     // even lanes hold (o, o+1)
                }
                if (((col & 1) == 0) && tvalid) {
                    const int op = ot * 8 + (col >> 1);
                    *(uint4*)&qk_p[(size_t)(b * 64 + op) * TT + t0 + 4 * quad] =
                        make_uint4(pk[0], pk[1], pk[2], pk[3]);
                }
            } else {                       // v: pair along t within lane
                if (tvalid) {
                    const int d = (ot - 8) * 16 + col;
                    uint2 u;
                    u.x = packbf2(val[0], val[1]);
                    u.y = packbf2(val[2], val[3]);
                    *(uint2*)&v_p[(size_t)(b * 64 + d) * 152 + 8 * tt + 2 * quad] = u;
                }
            }
        }
    }
}

// ---------------------------------------------------------------------------
// k_attn: relative-position attention per (b, h), MFMA. Updated: staging from
// pre-paired bf16 qkv (1 u32 load -> frag slot; V via b128->b128), key_rel
// fragments from precomputed table, tbuf stride 35, attnh stored bf16 t-paired.
// ---------------------------------------------------------------------------
__global__ __launch_bounds__(256) void k_attn(unsigned* __restrict__ W)
{
    const int bh = blockIdx.x;             // 0..1599
    const int b = bh >> 2, h = bh & 3;
    const int tid  = threadIdx.x;
    const int wave = tid >> 6, lane = tid & 63;
    const int col  = lane & 15, quad = lane >> 4;

    const unsigned* qk_p = W + WS_QK;
    const unsigned* v_p  = W + WS_V;
    unsigned* ah_p = W + WS_AH;
    const unsigned* relfrag = W + WS_REL;

    __shared__ unsigned kbuf[20 * 32 * 4];   // K B-frags, 10 KB
    __shared__ unsigned vbuf[10 * 64 * 4];   // V B-frags, 10 KB
    __shared__ float relbuf[4][16 * 67];     // rel ring, 17.2 KB
    __shared__ float tbuf[4][16 * 35];       // logits transpose, stride 35
    __shared__ float sbuf[4][16];

    // ---- stage K: 1 u32 (pre-paired along d) per frag slot ----
    for (int p = tid; p < 2560; p += 256) {
        const int c = p & 15, j2 = (p >> 4) & 3, qh = (p >> 6) & 1, st = p >> 7;
        kbuf[(st * 32 + qh * 16 + c) * 4 + j2] =
            qk_p[(size_t)(b * 64 + 32 + h * 8 + qh * 4 + j2) * TT + st * 16 + c];
    }
    // ---- stage V: b128 -> b128 (pre-paired along t = contraction dim) ----
    for (int p = tid; p < 640; p += 256) {
        const int tq = p % 40, c = p / 40;
        const uint4 u = *(const uint4*)&v_p[(size_t)(b * 64 + h * 16 + c) * 152 + tq * 4];
        *(uint4*)&vbuf[((tq >> 2) * 64 + (tq & 3) * 16 + c) * 4] = u;
    }
    __syncthreads();

    float* relw = &relbuf[wave][0];
    float* tw   = &tbuf[wave][0];
    const float4v zero4 = {0.f, 0.f, 0.f, 0.f};

    for (int tt = wave; tt < 19; tt += 4) {
        const int t0 = tt * 16;

        // ---- Q A-frag: 4 direct u32 loads (pre-paired, pre-scaled) ----
        U8 qf;
        if (quad < 2) {
            int t = t0 + col; if (t > TT - 1) t = TT - 1;
            const size_t rb = (size_t)(b * 64 + h * 8 + quad * 4) * TT + t;
            #pragma unroll
            for (int j2 = 0; j2 < 4; ++j2) qf.w[j2] = qk_p[rb + (size_t)j2 * TT];
        } else {
            qf.w[0] = qf.w[1] = qf.w[2] = qf.w[3] = 0u;
        }

        // ---- prologue: rel tiles (17-tt), (18-tt) ----
        #pragma unroll
        for (int i = 0; i < 2; ++i) {
            const int mt = 17 - tt + i;
            const uint4 u = *(const uint4*)&relfrag[(mt + 1) * 256 + lane * 4];
            U8 kr; kr.w[0] = u.x; kr.w[1] = u.y; kr.w[2] = u.z; kr.w[3] = u.w;
            const float4v rc = __builtin_amdgcn_mfma_f32_16x16x32_bf16(qf.v, kr.v, zero4, 0, 0, 0);
            const int slot = (mt & 3) * 16 + col;
            #pragma unroll
            for (int r = 0; r < 4; ++r) relw[(4 * quad + r) * 67 + slot] = rc[r];
        }

        float4v accPV = zero4;
        float  sumA = 0.f;

        #pragma unroll 1
        for (int c = 0; c < 10; ++c) {
            const int mt_lo = 2 * c - tt + 17;
            #pragma unroll
            for (int i = 2; i < 4; ++i) {
                const int mt = mt_lo + i;
                const uint4 u = *(const uint4*)&relfrag[(mt + 1) * 256 + lane * 4];
                U8 kr; kr.w[0] = u.x; kr.w[1] = u.y; kr.w[2] = u.z; kr.w[3] = u.w;
                const float4v rc = __builtin_amdgcn_mfma_f32_16x16x32_bf16(qf.v, kr.v, zero4, 0, 0, 0);
                const int slot = (mt & 3) * 16 + col;
                #pragma unroll
                for (int r = 0; r < 4; ++r) relw[(4 * quad + r) * 67 + slot] = rc[r];
            }

            // ---- QK for the two s-tiles of this chunk ----
            float4v qk[2];
            #pragma unroll
            for (int sti = 0; sti < 2; ++sti) {
                const int st = 2 * c + sti;
                short8 kf;
                if (quad < 2) {
                    kf = *(const short8*)&kbuf[(st * 32 + quad * 16 + col) * 4];
                } else {
                    U8 z; z.w[0] = z.w[1] = z.w[2] = z.w[3] = 0u; kf = z.v;
                }
                qk[sti] = __builtin_amdgcn_mfma_f32_16x16x32_bf16(qf.v, kf, zero4, 0, 0, 0);
            }

            // ---- C-layout: add rel (ring gather), park in tbuf ----
            #pragma unroll
            for (int sti = 0; sti < 2; ++sti) {
                const int s = (2 * c + sti) * 16 + col;
                #pragma unroll
                for (int r = 0; r < 4; ++r) {
                    const int row = 4 * quad + r;
                    const int m = s - (t0 + row) + (TT - 1);
                    const float rel = relw[row * 67 + ((m >> 4) & 3) * 16 + (m & 15)];
                    tw[row * 35 + sti * 16 + col] = qk[sti][r] + rel;
                }
            }

            // ---- A-layout: exp, row-sum partial, pack P frag ----
            const int ka = quad * 8;
            U8 pf;
            #pragma unroll
            for (int j2 = 0; j2 < 4; ++j2) {
                float p0 = tw[col * 35 + ka + 2 * j2];
                float p1 = tw[col * 35 + ka + 2 * j2 + 1];
                p0 = (32 * c + ka + 2 * j2     < TT) ? __expf(p0) : 0.f;
                p1 = (32 * c + ka + 2 * j2 + 1 < TT) ? __expf(p1) : 0.f;
                sumA += p0 + p1;
                pf.w[j2] = packbf2(p0, p1);
            }
            const short8 vf = *(const short8*)&vbuf[(c * 64 + lane) * 4];
            accPV = __builtin_amdgcn_mfma_f32_16x16x32_bf16(pf.v, vf, accPV, 0, 0, 0);
        }

        // ---- finalize: row sums, normalize, bf16 t-paired store ----
        sumA += __shfl_xor(sumA, 16, 64);
        sumA += __shfl_xor(sumA, 32, 64);
        if (lane < 16) sbuf[wave][lane] = sumA;
        const float4 rs = *(const float4*)&sbuf[wave][4 * quad];
        if (t0 + 4 * quad + 3 < TT) {
            uint2 u;
            u.x = packbf2(accPV[0] / rs.x, accPV[1] / rs.y);
            u.y = packbf2(accPV[2] / rs.z, accPV[3] / rs.w);
            *(uint2*)&ah_p[(size_t)(b * 64 + h * 16 + col) * 152 + 8 * tt + 2 * quad] = u;
        }
    }
}

// ---------------------------------------------------------------------------
// k_out (MFMA): per (t-tile, n). C[v][o] tiles so skip-read/store are
// v-contiguous; attnh staged via swizzled LDS frag buffer (64 KB).
// out = relu(gemm' + x*scO + aoff), gemm' has bn-scale folded into weights.
// ---------------------------------------------------------------------------
__global__ __launch_bounds__(256) void k_out(
        const float* __restrict__ x, const unsigned* __restrict__ W,
        float* __restrict__ out)
{
    const int tt = blockIdx.x, n = blockIdx.y, t0 = tt * 16;
    const int tid = threadIdx.x;
    const unsigned* ah_p = W + WS_AH;
    const unsigned* awfrag = W + WS_AWF;
    const float* aoff = (const float*)(W + WS_AOFF);
    const float* scO  = (const float*)(W + WS_SCO);

    __shared__ unsigned fbuf[16 * 1024];   // 64 KB, +12t swizzle, col^quad

    for (int i = tid; i < 6400; i += 256) {
        const int tp = i & 7, pc = (i >> 3) & 31, v = i >> 8;
        const int b = n * 25 + v;
        const size_t r0 = (size_t)(b * 64 + 2 * pc) * 152 + tt * 8 + tp;
        const unsigned A = ah_p[r0], Bv = ah_p[r0 + 152];
        const unsigned ue = (A & 0xFFFFu) | (Bv << 16);
        const unsigned uo = (A >> 16) | (Bv & 0xFFFF0000u);
        const int vt = v >> 4, cv = v & 15, ch = pc >> 4, qd = (pc >> 2) & 3, j2 = pc & 3;
        const int xi = (vt * 2 + ch) * 256 + (qd * 16 + (cv ^ qd)) * 4 + j2;
        const int tl = 2 * tp;
        fbuf[tl * 1024 + ((xi + 12 * tl) & 1023)]             = ue;
        fbuf[(tl + 1) * 1024 + ((xi + 12 * (tl + 1)) & 1023)] = uo;
    }
    __syncthreads();

    const int wv = tid >> 6, lane = tid & 63, col = lane & 15, quad = lane >> 4;
    const int o = wv * 16 + col;
    const float4v zero4 = {0.f, 0.f, 0.f, 0.f};

    U8 awf0, awf1;
    { const uint4 u = *(const uint4*)&awfrag[(wv * 2 + 0) * 256 + lane * 4];
      awf0.w[0] = u.x; awf0.w[1] = u.y; awf0.w[2] = u.z; awf0.w[3] = u.w; }
    { const uint4 u = *(const uint4*)&awfrag[(wv * 2 + 1) * 256 + lane * 4];
      awf1.w[0] = u.x; awf1.w[1] = u.y; awf1.w[2] = u.z; awf1.w[3] = u.w; }
    const float aoff_l = aoff[o], sc_l = scO[o];
    const int tmax = (tt == 18) ? 12 : 16;

    for (int tl = 0; tl < tmax; ++tl) {
        const int t = t0 + tl;
        #pragma unroll
        for (int vt = 0; vt < 2; ++vt) {
            U8 a0, a1;
            { const int xb = (vt * 2 + 0) * 256 + (quad * 16 + (col ^ quad)) * 4;
              const uint4 u = *(const uint4*)&fbuf[tl * 1024 + ((xb + 12 * tl) & 1023)];
              a0.w[0] = u.x; a0.w[1] = u.y; a0.w[2] = u.z; a0.w[3] = u.w; }
            { const int xb = (vt * 2 + 1) * 256 + (quad * 16 + (col ^ quad)) * 4;
              const uint4 u = *(const uint4*)&fbuf[tl * 1024 + ((xb + 12 * tl) & 1023)];
              a1.w[0] = u.x; a1.w[1] = u.y; a1.w[2] = u.z; a1.w[3] = u.w; }
            float4v acc = __builtin_amdgcn_mfma_f32_16x16x32_bf16(a0.v, awf0.v, zero4, 0, 0, 0);
            acc = __builtin_amdgcn_mfma_f32_16x16x32_bf16(a1.v, awf1.v, acc, 0, 0, 0);
            #pragma unroll
            for (int r = 0; r < 4; ++r) {
                const int v = vt * 16 + 4 * quad + r;
                if (v < 25) {
                    const size_t xidx = ((size_t)(n * 64 + o) * TT + t) * 25 + v;
                    const float val = acc[r] + x[xidx] * sc_l + aoff_l;
                    out[xidx] = fmaxf(val, 0.f);
                }
            }
        }
    }
}

// ---------------------------------------------------------------------------
extern "C" void kernel_launch(void* const* d_in, const int* in_sizes, int n_in,
                              void* d_out, int out_size, void* d_ws, size_t ws_size,
                              hipStream_t stream)
{
    const float* x       = (const float*)d_in[0];
    const float* dbn_g   = (const float*)d_in[1];
    const float* dbn_b   = (const float*)d_in[2];
    const float* dbn_m   = (const float*)d_in[3];
    const float* dbn_v   = (const float*)d_in[4];
    const float* qkv_w   = (const float*)d_in[5];
    const float* qkv_b   = (const float*)d_in[6];
    const float* key_rel = (const float*)d_in[7];
    const float* attn_w  = (const float*)d_in[8];
    const float* attn_b  = (const float*)d_in[9];
    const float* bn_g    = (const float*)d_in[10];
    const float* bn_b    = (const float*)d_in[11];
    const float* bn_m    = (const float*)d_in[12];
    const float* bn_v    = (const float*)d_in[13];
    float* out = (float*)d_out;
    unsigned* W = (unsigned*)d_ws;

    k_pre<<<26, 256, 0, stream>>>(dbn_g, dbn_b, dbn_m, dbn_v, qkv_w, qkv_b,
                                  key_rel, attn_w, attn_b, bn_g, bn_b, bn_m,
                                  bn_v, W);
    k_qkv<<<dim3(19, 16), 256, 0, stream>>>(x, W);
    k_attn<<<dim3(BB * NHH), 256, 0, stream>>>(W);
    k_out<<<dim3(19, 16), 256, 0, stream>>>(x, W, out);
}

// Round 4
// 290.212 us; speedup vs baseline: 6.4683x; 1.1763x over previous
//
#include <hip/hip_runtime.h>
#include <hip/hip_bf16.h>
#include <cstddef>

// Problem constants
#define NN 16
#define CC 64
#define TT 300
#define VV 25
#define NHH 4
#define DKHH 16
#define BB (NN * VV)          // 400
#define EPS 1e-5f

// Workspace layout (u32 units)
#define WS_QK    0            // u32[400][64][300]  q|k bf16, paired along o
#define WS_V     7680000      // u32[400][64][152]  v bf16, paired along t
#define WS_AH    11571200     // u32[400][64][152]  attnh bf16, paired along t
#define WS_SCSH  15462400     // float2[1600] data_bn (sc, sh) per (c, v)
#define WS_WFRAG 15465600     // u32[12][2][64][4] qkv_w B-frags (q rows pre-scaled 0.25)
#define WS_QB2   15471744     // f32[192] qkv_b (q pre-scaled 0.25)
#define WS_AWF   15471936     // u32[4][2][64][4] attn_w B-frags (pre-scaled by bn scale)
#define WS_AOFF  15473984     // f32[64] fused attn_b+bn offset
#define WS_SCO   15474048     // f32[64] bn scale (for skip path)
#define WS_REL   15474112     // u32[41][64][4] key_rel frags (slot = mtile+1, slot0 = zeros)

typedef __attribute__((ext_vector_type(8))) short short8;
typedef __attribute__((ext_vector_type(4))) float float4v;

union U8 { short8 v; unsigned int w[4]; };

// f32x2 -> packed bf16x2 (RNE). HW op if available, else manual.
__device__ __forceinline__ unsigned int pk2(float a, float b) {
#if __has_builtin(__builtin_amdgcn_cvt_pk_bf16_f32)
    typedef __attribute__((ext_vector_type(2))) __bf16 bf2;
    union { bf2 v; unsigned u; } c;
    c.v = __builtin_amdgcn_cvt_pk_bf16_f32(a, b);
    return c.u;
#else
    union { float f; unsigned u; } x, y;
    x.f = a; y.f = b;
    unsigned ua = x.u + 0x7FFFu + ((x.u >> 16) & 1u);
    unsigned ub = y.u + 0x7FFFu + ((y.u >> 16) & 1u);
    return (ua >> 16) | (ub & 0xFFFF0000u);
#endif
}

// ---------------------------------------------------------------------------
// k_pre: constant tables (unchanged from R3)
// ---------------------------------------------------------------------------
__global__ __launch_bounds__(256) void k_pre(
    const float* __restrict__ dbn_g, const float* __restrict__ dbn_b,
    const float* __restrict__ dbn_m, const float* __restrict__ dbn_v,
    const float* __restrict__ qkv_w, const float* __restrict__ qkv_b,
    const float* __restrict__ key_rel,
    const float* __restrict__ attn_w, const float* __restrict__ attn_b,
    const float* __restrict__ bn_g, const float* __restrict__ bn_b,
    const float* __restrict__ bn_m, const float* __restrict__ bn_v,
    unsigned* __restrict__ W)
{
    const int jid = blockIdx.x * 256 + threadIdx.x;
    if (jid < 2624) {                      // relfrag: 41 slots x 64 lanes
        const int k = jid >> 6, lane = jid & 63, col = lane & 15, quad = lane >> 4;
        const int mt = k - 1, m = mt * 16 + col;
        const bool ok = (quad < 2) && (mt >= 0) && (m < 2 * TT - 1);
        unsigned w[4];
        #pragma unroll
        for (int j2 = 0; j2 < 4; ++j2) {
            const int c = quad * 8 + 2 * j2;
            const float v0 = ok ? key_rel[m * 16 + c] : 0.f;
            const float v1 = ok ? key_rel[m * 16 + c + 1] : 0.f;
            w[j2] = pk2(v0, v1);
        }
        *(uint4*)&W[WS_REL + k * 256 + lane * 4] = make_uint4(w[0], w[1], w[2], w[3]);
    } else if (jid < 4160) {               // wfrag: 12 otiles x 2 chalf x 64
        const int e = jid - 2624;
        const int ot = e >> 7, ch = (e >> 6) & 1, lane = e & 63;
        const int col = lane & 15, quad = lane >> 4;
        const int o = ot * 16 + col;
        const float s = (o < 64) ? 0.25f : 1.f;
        unsigned w[4];
        #pragma unroll
        for (int j2 = 0; j2 < 4; ++j2) {
            const int c = ch * 32 + quad * 8 + 2 * j2;
            w[j2] = pk2(qkv_w[o * 64 + c] * s, qkv_w[o * 64 + c + 1] * s);
        }
        *(uint4*)&W[WS_WFRAG + (ot * 2 + ch) * 256 + lane * 4] = make_uint4(w[0], w[1], w[2], w[3]);
    } else if (jid < 4672) {               // awfrag: 4 otiles x 2 chalf x 64
        const int e = jid - 4160;
        const int ot = e >> 7, ch = (e >> 6) & 1, lane = e & 63;
        const int col = lane & 15, quad = lane >> 4;
        const int o = ot * 16 + col;
        const float sc = bn_g[o] * rsqrtf(bn_v[o] + EPS);
        unsigned w[4];
        #pragma unroll
        for (int j2 = 0; j2 < 4; ++j2) {
            const int c = ch * 32 + quad * 8 + 2 * j2;
            w[j2] = pk2(attn_w[o * 64 + c] * sc, attn_w[o * 64 + c + 1] * sc);
        }
        *(uint4*)&W[WS_AWF + (ot * 2 + ch) * 256 + lane * 4] = make_uint4(w[0], w[1], w[2], w[3]);
    } else if (jid < 4864) {               // qb2
        const int o = jid - 4672;
        ((float*)(W + WS_QB2))[o] = qkv_b[o] * ((o < 64) ? 0.25f : 1.f);
    } else if (jid < 4928) {               // aoff
        const int o = jid - 4864;
        const float sc = bn_g[o] * rsqrtf(bn_v[o] + EPS);
        ((float*)(W + WS_AOFF))[o] = attn_b[o] * sc + bn_b[o] - bn_m[o] * sc;
    } else if (jid < 4992) {               // scO
        const int o = jid - 4928;
        ((float*)(W + WS_SCO))[o] = bn_g[o] * rsqrtf(bn_v[o] + EPS);
    } else if (jid < 6592) {               // data_bn sc/sh per (c*25+v)
        const int e = jid - 4992;
        const float sc = dbn_g[e] * rsqrtf(dbn_v[e] + EPS);
        const float sh = dbn_b[e] - dbn_m[e] * sc;
        ((float2*)(W + WS_SCSH))[e] = make_float2(sc, sh);
    }
}

// ---------------------------------------------------------------------------
// k_qkv (MFMA): per (t-tile, n). 512 threads / 8 waves; wave = (otg, vhalf).
// ---------------------------------------------------------------------------
__global__ __launch_bounds__(512) void k_qkv(
        const float* __restrict__ x, unsigned* __restrict__ W)
{
    const int tt = blockIdx.x, n = blockIdx.y, t0 = tt * 16;
    const int tid = threadIdx.x;
    const float2* scsh = (const float2*)(W + WS_SCSH);
    const unsigned* wfrag = W + WS_WFRAG;
    const float* qb2 = (const float*)(W + WS_QB2);
    unsigned* qk_p = W + WS_QK;
    unsigned* v_p  = W + WS_V;

    __shared__ unsigned afrag[12896];      // v-stride 516

    for (int i = tid; i < 12800; i += 512) {
        const int v = i % 25, rest = i / 25;
        const int tcol = rest & 15, pc = rest >> 4;
        const int ch = pc >> 4, quad = (pc >> 2) & 3, j2 = pc & 3;
        const int c0 = pc * 2;
        const int t = t0 + tcol;
        float a0 = 0.f, a1 = 0.f;
        if (t < TT) {
            const size_t base = ((size_t)(n * 64 + c0) * TT + t) * 25 + v;
            const float2 s0 = scsh[c0 * 25 + v];
            const float2 s1 = scsh[c0 * 25 + 25 + v];
            a0 = fmaf(x[base], s0.x, s0.y);
            a1 = fmaf(x[base + 7500], s1.x, s1.y);
        }
        afrag[v * 516 + (ch * 64 + quad * 16 + tcol) * 4 + j2] = pk2(a0, a1);
    }
    __syncthreads();

    const int wv = tid >> 6, lane = tid & 63, col = lane & 15, quad = lane >> 4;
    const int otg = wv >> 1, vh = wv & 1;
    const int vlo = 13 * vh, vhi = vh ? 25 : 13;
    const float4v zero4 = {0.f, 0.f, 0.f, 0.f};

    U8 bf[3][2]; float qb_l[3];
    #pragma unroll
    for (int i = 0; i < 3; ++i) {
        const int ot = 3 * otg + i;
        #pragma unroll
        for (int ch = 0; ch < 2; ++ch) {
            const uint4 u = *(const uint4*)&wfrag[(ot * 2 + ch) * 256 + lane * 4];
            bf[i][ch].w[0] = u.x; bf[i][ch].w[1] = u.y; bf[i][ch].w[2] = u.z; bf[i][ch].w[3] = u.w;
        }
        qb_l[i] = qb2[ot * 16 + col];
    }
    const bool tvalid = (t0 + 4 * quad + 3 < TT);

    for (int v = vlo; v < vhi; ++v) {
        const int b = n * 25 + v;
        U8 a0, a1;
        { const uint4 u = *(const uint4*)&afrag[v * 516 + lane * 4];
          a0.w[0] = u.x; a0.w[1] = u.y; a0.w[2] = u.z; a0.w[3] = u.w; }
        { const uint4 u = *(const uint4*)&afrag[v * 516 + 256 + lane * 4];
          a1.w[0] = u.x; a1.w[1] = u.y; a1.w[2] = u.z; a1.w[3] = u.w; }
        #pragma unroll
        for (int i = 0; i < 3; ++i) {
            const int ot = 3 * otg + i;
            float4v acc = __builtin_amdgcn_mfma_f32_16x16x32_bf16(a0.v, bf[i][0].v, zero4, 0, 0, 0);
            acc = __builtin_amdgcn_mfma_f32_16x16x32_bf16(a1.v, bf[i][1].v, acc, 0, 0, 0);
            float val[4];
            #pragma unroll
            for (int r = 0; r < 4; ++r) val[r] = acc[r] + qb_l[i];
            if (ot < 8) {                  // q|k: pair neighbor o lanes
                unsigned pk[4];
                #pragma unroll
                for (int r = 0; r < 4; ++r) {
                    const float p = __shfl_xor(val[r], 1);
                    pk[r] = pk2(val[r], p);
                }
                if (((col & 1) == 0) && tvalid) {
                    const int op = ot * 8 + (col >> 1);
                    *(uint4*)&qk_p[(size_t)(b * 64 + op) * TT + t0 + 4 * quad] =
                        make_uint4(pk[0], pk[1], pk[2], pk[3]);
                }
            } else {                       // v: pair along t within lane
                if (tvalid) {
                    const int d = (ot - 8) * 16 + col;
                    uint2 u;
                    u.x = pk2(val[0], val[1]);
                    u.y = pk2(val[2], val[3]);
                    *(uint2*)&v_p[(size_t)(b * 64 + d) * 152 + 8 * tt + 2 * quad] = u;
                }
            }
        }
    }
}

// ---------------------------------------------------------------------------
// k_attn (K·Q^T restructure): C rows = s, cols = t. Per s-tile: 1 rel MFMA
// into a [t][m] ring (b128 store, linear gather via 3-entry dup), 1 QK MFMA,
// exp in C-layout, quad-local shfl transpose -> PV A-frag. No tbuf.
// LDS 37.6 KB -> 4 blocks/CU.
// ---------------------------------------------------------------------------
__global__ __launch_bounds__(256) void k_attn(unsigned* __restrict__ W)
{
    const int bh = blockIdx.x;             // 0..1599
    const int b = bh >> 2, h = bh & 3;
    const int tid  = threadIdx.x;
    const int wave = tid >> 6, lane = tid & 63;
    const int col  = lane & 15, quad = lane >> 4;

    const unsigned* qk_p = W + WS_QK;
    const unsigned* v_p  = W + WS_V;
    unsigned* ah_p = W + WS_AH;
    const unsigned* relfrag = W + WS_REL;

    __shared__ unsigned kbuf[19 * 32 * 4];   // 9.7 KB
    __shared__ unsigned vbuf[10 * 64 * 4];   // 10.2 KB
    __shared__ float relbuf[4][16 * 68];     // [t][m-ring+dup], 17.4 KB
    __shared__ float sbuf[4][16];

    // ---- stage K (19 s-tiles) ----
    for (int p = tid; p < 2432; p += 256) {
        const int c = p & 15, j2 = (p >> 4) & 3, qh = (p >> 6) & 1, st = p >> 7;
        kbuf[(st * 32 + qh * 16 + c) * 4 + j2] =
            qk_p[(size_t)(b * 64 + 32 + h * 8 + qh * 4 + j2) * TT + st * 16 + c];
    }
    // ---- stage V ----
    for (int p = tid; p < 640; p += 256) {
        const int tq = p % 40, c = p / 40;
        const uint4 u = *(const uint4*)&v_p[(size_t)(b * 64 + h * 16 + c) * 152 + tq * 4];
        *(uint4*)&vbuf[((tq >> 2) * 64 + (tq & 3) * 16 + c) * 4] = u;
    }
    __syncthreads();

    float* relw = &relbuf[wave][0];
    const float4v zero4 = {0.f, 0.f, 0.f, 0.f};

    for (int tt = wave; tt < 19; tt += 4) {
        const int t0 = tt * 16;

        // ---- Q B-frag (cols = t) ----
        U8 qf;
        if (quad < 2) {
            int t = t0 + col; if (t > TT - 1) t = TT - 1;
            const size_t rb = (size_t)(b * 64 + h * 8 + quad * 4) * TT + t;
            qf.w[0] = qk_p[rb];
            qf.w[1] = qk_p[rb + TT];
            qf.w[2] = qk_p[rb + 2 * TT];
            qf.w[3] = qk_p[rb + 3 * TT];
        } else {
            qf.w[0] = qf.w[1] = qf.w[2] = qf.w[3] = 0u;
        }

        // rel producer: REL'[m][t] tile mt -> ring row [t=col], b128 store
        auto relprod = [&](int mt) {
            const uint4 u = *(const uint4*)&relfrag[(mt + 1) * 256 + lane * 4];
            U8 kr; kr.w[0] = u.x; kr.w[1] = u.y; kr.w[2] = u.z; kr.w[3] = u.w;
            const float4v rc = __builtin_amdgcn_mfma_f32_16x16x32_bf16(
                                   kr.v, qf.v, zero4, 0, 0, 0);
            const float4 st4 = make_float4(rc[0], rc[1], rc[2], rc[3]);
            *(float4*)&relw[col * 68 + ((mt & 3) * 16 + quad * 4)] = st4;
            if (((mt & 3) == 0) && (quad == 0))          // dup for linear gather
                *(float4*)&relw[col * 68 + 64] = st4;
        };
        relprod(17 - tt);
        relprod(18 - tt);

        float4v accPV = zero4;
        float sumA = 0.f;
        unsigned p0s[2] = {0u, 0u}, p1s[2] = {0u, 0u};

        #pragma unroll 1
        for (int st = 0; st < 19; ++st) {
            relprod(st - tt + 19);

            // ---- QK' = K·Q^T: rows s, cols t ----
            U8 kf;
            if (quad < 2) {
                const uint4 u = *(const uint4*)&kbuf[(st * 32 + quad * 16 + col) * 4];
                kf.w[0] = u.x; kf.w[1] = u.y; kf.w[2] = u.z; kf.w[3] = u.w;
            } else {
                kf.w[0] = kf.w[1] = kf.w[2] = kf.w[3] = 0u;
            }
            const float4v qk = __builtin_amdgcn_mfma_f32_16x16x32_bf16(
                                   kf.v, qf.v, zero4, 0, 0, 0);

            // ---- gather rel (4 linear reads), exp in C-layout ----
            const int m_b = st * 16 + 4 * quad - t0 - col + (TT - 1);
            const float* rp = &relw[col * 68 + (m_b & 63)];
            float e0 = __expf(qk[0] + rp[0]);
            float e1 = __expf(qk[1] + rp[1]);
            float e2 = __expf(qk[2] + rp[2]);
            float e3 = __expf(qk[3] + rp[3]);
            if (st == 18 && quad == 3) { e0 = e1 = e2 = e3 = 0.f; }  // s>=300
            sumA += (e0 + e1) + (e2 + e3);

            const int sti = st & 1;
            p0s[sti] = pk2(e0, e1);
            p1s[sti] = pk2(e2, e3);

            if (sti == 1 || st == 18) {
                if (st == 18) { p0s[1] = 0u; p1s[1] = 0u; }
                // quad-local transpose: C(s,t) packs -> PV A-frag P[t][s]
                const int lA = ((2 * quad) & 3) * 16 + col;
                const int lB = ((2 * quad + 1) & 3) * 16 + col;
                const unsigned a0 = (unsigned)__shfl((int)p0s[0], lA, 64);
                const unsigned b0 = (unsigned)__shfl((int)p0s[1], lA, 64);
                const unsigned a1 = (unsigned)__shfl((int)p1s[0], lA, 64);
                const unsigned b1 = (unsigned)__shfl((int)p1s[1], lA, 64);
                const unsigned a2 = (unsigned)__shfl((int)p0s[0], lB, 64);
                const unsigned b2 = (unsigned)__shfl((int)p0s[1], lB, 64);
                const unsigned a3 = (unsigned)__shfl((int)p1s[0], lB, 64);
                const unsigned b3 = (unsigned)__shfl((int)p1s[1], lB, 64);
                U8 pf;
                pf.w[0] = (quad < 2) ? a0 : b0;
                pf.w[1] = (quad < 2) ? a1 : b1;
                pf.w[2] = (quad < 2) ? a2 : b2;
                pf.w[3] = (quad < 2) ? a3 : b3;
                const short8 vf = *(const short8*)&vbuf[((st >> 1) * 64 + lane) * 4];
                accPV = __builtin_amdgcn_mfma_f32_16x16x32_bf16(pf.v, vf, accPV, 0, 0, 0);
            }
        }

        // ---- finalize: row sums, normalize, bf16 t-paired store ----
        sumA += __shfl_xor(sumA, 16, 64);
        sumA += __shfl_xor(sumA, 32, 64);
        if (lane < 16) sbuf[wave][lane] = sumA;
        const float4 rs = *(const float4*)&sbuf[wave][4 * quad];
        if (t0 + 4 * quad + 3 < TT) {
            uint2 u;
            u.x = pk2(accPV[0] / rs.x, accPV[1] / rs.y);
            u.y = pk2(accPV[2] / rs.z, accPV[3] / rs.w);
            *(uint2*)&ah_p[(size_t)(b * 64 + h * 16 + col) * 152 + 8 * tt + 2 * quad] = u;
        }
    }
}

// ---------------------------------------------------------------------------
// k_out (MFMA): per (t-tile/2, n, half). 8 t per block, 32 KB LDS, grid 608.
// ---------------------------------------------------------------------------
__global__ __launch_bounds__(256) void k_out(
        const float* __restrict__ x, const unsigned* __restrict__ W,
        float* __restrict__ out)
{
    const int tt = blockIdx.x, n = blockIdx.y, half = blockIdx.z;
    const int t0 = tt * 16;
    const int tid = threadIdx.x;
    const unsigned* ah_p = W + WS_AH;
    const unsigned* awfrag = W + WS_AWF;
    const float* aoff = (const float*)(W + WS_AOFF);
    const float* scO  = (const float*)(W + WS_SCO);

    __shared__ unsigned fbuf[8 * 1024];    // 32 KB, +12t swizzle, col^quad

    for (int i = tid; i < 3200; i += 256) {
        const int tp = i & 3, pc = (i >> 2) & 31, v = i >> 7;
        const int b = n * 25 + v;
        const size_t r0 = (size_t)(b * 64 + 2 * pc) * 152 + tt * 8 + half * 4 + tp;
        const unsigned A = ah_p[r0], Bv = ah_p[r0 + 152];
        const unsigned ue = (A & 0xFFFFu) | (Bv << 16);
        const unsigned uo = (A >> 16) | (Bv & 0xFFFF0000u);
        const int vt = v >> 4, cv = v & 15, ch = pc >> 4, qd = (pc >> 2) & 3, j2 = pc & 3;
        const int xi = (vt * 2 + ch) * 256 + (qd * 16 + (cv ^ qd)) * 4 + j2;
        const int tl = 2 * tp;
        fbuf[tl * 1024 + ((xi + 12 * tl) & 1023)]             = ue;
        fbuf[(tl + 1) * 1024 + ((xi + 12 * (tl + 1)) & 1023)] = uo;
    }
    __syncthreads();

    const int wv = tid >> 6, lane = tid & 63, col = lane & 15, quad = lane >> 4;
    const int o = wv * 16 + col;
    const float4v zero4 = {0.f, 0.f, 0.f, 0.f};

    U8 awf0, awf1;
    { const uint4 u = *(const uint4*)&awfrag[(wv * 2 + 0) * 256 + lane * 4];
      awf0.w[0] = u.x; awf0.w[1] = u.y; awf0.w[2] = u.z; awf0.w[3] = u.w; }
    { const uint4 u = *(const uint4*)&awfrag[(wv * 2 + 1) * 256 + lane * 4];
      awf1.w[0] = u.x; awf1.w[1] = u.y; awf1.w[2] = u.z; awf1.w[3] = u.w; }
    const float aoff_l = aoff[o], sc_l = scO[o];
    const int tmax = (tt == 18 && half == 1) ? 4 : 8;

    for (int tl = 0; tl < tmax; ++tl) {
        const int t = t0 + 8 * half + tl;
        #pragma unroll
        for (int vt = 0; vt < 2; ++vt) {
            U8 a0, a1;
            { const int xb = (vt * 2 + 0) * 256 + (quad * 16 + (col ^ quad)) * 4;
              const uint4 u = *(const uint4*)&fbuf[tl * 1024 + ((xb + 12 * tl) & 1023)];
              a0.w[0] = u.x; a0.w[1] = u.y; a0.w[2] = u.z; a0.w[3] = u.w; }
            { const int xb = (vt * 2 + 1) * 256 + (quad * 16 + (col ^ quad)) * 4;
              const uint4 u = *(const uint4*)&fbuf[tl * 1024 + ((xb + 12 * tl) & 1023)];
              a1.w[0] = u.x; a1.w[1] = u.y; a1.w[2] = u.z; a1.w[3] = u.w; }
            float4v acc = __builtin_amdgcn_mfma_f32_16x16x32_bf16(a0.v, awf0.v, zero4, 0, 0, 0);
            acc = __builtin_amdgcn_mfma_f32_16x16x32_bf16(a1.v, awf1.v, acc, 0, 0, 0);
            #pragma unroll
            for (int r = 0; r < 4; ++r) {
                const int v = vt * 16 + 4 * quad + r;
                if (v < 25) {
                    const size_t xidx = ((size_t)(n * 64 + o) * TT + t) * 25 + v;
                    const float val = acc[r] + x[xidx] * sc_l + aoff_l;
                    out[xidx] = fmaxf(val, 0.f);
                }
            }
        }
    }
}

// ---------------------------------------------------------------------------
extern "C" void kernel_launch(void* const* d_in, const int* in_sizes, int n_in,
                              void* d_out, int out_size, void* d_ws, size_t ws_size,
                              hipStream_t stream)
{
    const float* x       = (const float*)d_in[0];
    const float* dbn_g   = (const float*)d_in[1];
    const float* dbn_b   = (const float*)d_in[2];
    const float* dbn_m   = (const float*)d_in[3];
    const float* dbn_v   = (const float*)d_in[4];
    const float* qkv_w   = (const float*)d_in[5];
    const float* qkv_b   = (const float*)d_in[6];
    const float* key_rel = (const float*)d_in[7];
    const float* attn_w  = (const float*)d_in[8];
    const float* attn_b  = (const float*)d_in[9];
    const float* bn_g    = (const float*)d_in[10];
    const float* bn_b    = (const float*)d_in[11];
    const float* bn_m    = (const float*)d_in[12];
    const float* bn_v    = (const float*)d_in[13];
    float* out = (float*)d_out;
    unsigned* W = (unsigned*)d_ws;

    k_pre<<<26, 256, 0, stream>>>(dbn_g, dbn_b, dbn_m, dbn_v, qkv_w, qkv_b,
                                  key_rel, attn_w, attn_b, bn_g, bn_b, bn_m,
                                  bn_v, W);
    k_qkv<<<dim3(19, 16), 512, 0, stream>>>(x, W);
    k_attn<<<dim3(BB * NHH), 256, 0, stream>>>(W);
    k_out<<<dim3(19, 16, 2), 256, 0, stream>>>(x, W, out);
}

// Round 5
// 283.682 us; speedup vs baseline: 6.6172x; 1.0230x over previous
//
#include <hip/hip_runtime.h>
#include <hip/hip_bf16.h>
#include <cstddef>

// Problem constants
#define NN 16
#define CC 64
#define TT 300
#define VV 25
#define NHH 4
#define DKHH 16
#define BB (NN * VV)          // 400
#define EPS 1e-5f
#define LOG2E 1.4426950408889634f

// Workspace layout (u32 units)
#define WS_QK    0            // u32[400][64][300]  q|k bf16, paired along o (q pre-scaled 0.25*log2e)
#define WS_V     7680000      // u32[400][64][152]  v bf16, paired along t (t>=300 zero-filled)
#define WS_AH    11571200     // u32[400][64][152]  attnh bf16, paired along t
#define WS_SCSH  15462400     // float2[1600] data_bn (sc, sh) per (c, v)
#define WS_WFRAG 15465600     // u32[12][2][64][4] qkv_w B-frags
#define WS_QB2   15471744     // f32[192] qkv_b (q pre-scaled)
#define WS_AWF   15471936     // u32[4][2][64][4] attn_w B-frags (pre-scaled by bn scale)
#define WS_AOFF  15473984     // f32[64] fused attn_b+bn offset
#define WS_SCO   15474048     // f32[64] bn scale (for skip path)
#define WS_REL   15474112     // u32[41][64][4] key_rel frags (slot = mtile+1, slot0 = zeros)

typedef __attribute__((ext_vector_type(8))) short short8;
typedef __attribute__((ext_vector_type(4))) float float4v;

union U8 { short8 v; unsigned int w[4]; };

// f32x2 -> packed bf16x2 (RNE). HW op if available, else manual.
__device__ __forceinline__ unsigned int pk2(float a, float b) {
#if __has_builtin(__builtin_amdgcn_cvt_pk_bf16_f32)
    typedef __attribute__((ext_vector_type(2))) __bf16 bf2;
    union { bf2 v; unsigned u; } c;
    c.v = __builtin_amdgcn_cvt_pk_bf16_f32(a, b);
    return c.u;
#else
    union { float f; unsigned u; } x, y;
    x.f = a; y.f = b;
    unsigned ua = x.u + 0x7FFFu + ((x.u >> 16) & 1u);
    unsigned ub = y.u + 0x7FFFu + ((y.u >> 16) & 1u);
    return (ua >> 16) | (ub & 0xFFFF0000u);
#endif
}

// ---------------------------------------------------------------------------
// k_pre: constant tables. q rows now pre-scaled by 0.25*log2e so the attn
// softmax uses exp2 directly (both q.k and q.key_rel inherit the scale).
// ---------------------------------------------------------------------------
__global__ __launch_bounds__(256) void k_pre(
    const float* __restrict__ dbn_g, const float* __restrict__ dbn_b,
    const float* __restrict__ dbn_m, const float* __restrict__ dbn_v,
    const float* __restrict__ qkv_w, const float* __restrict__ qkv_b,
    const float* __restrict__ key_rel,
    const float* __restrict__ attn_w, const float* __restrict__ attn_b,
    const float* __restrict__ bn_g, const float* __restrict__ bn_b,
    const float* __restrict__ bn_m, const float* __restrict__ bn_v,
    unsigned* __restrict__ W)
{
    const int jid = blockIdx.x * 256 + threadIdx.x;
    if (jid < 2624) {                      // relfrag: 41 slots x 64 lanes
        const int k = jid >> 6, lane = jid & 63, col = lane & 15, quad = lane >> 4;
        const int mt = k - 1, m = mt * 16 + col;
        const bool ok = (quad < 2) && (mt >= 0) && (m < 2 * TT - 1);
        unsigned w[4];
        #pragma unroll
        for (int j2 = 0; j2 < 4; ++j2) {
            const int c = quad * 8 + 2 * j2;
            const float v0 = ok ? key_rel[m * 16 + c] : 0.f;
            const float v1 = ok ? key_rel[m * 16 + c + 1] : 0.f;
            w[j2] = pk2(v0, v1);
        }
        *(uint4*)&W[WS_REL + k * 256 + lane * 4] = make_uint4(w[0], w[1], w[2], w[3]);
    } else if (jid < 4160) {               // wfrag
        const int e = jid - 2624;
        const int ot = e >> 7, ch = (e >> 6) & 1, lane = e & 63;
        const int col = lane & 15, quad = lane >> 4;
        const int o = ot * 16 + col;
        const float s = (o < 64) ? 0.25f * LOG2E : 1.f;
        unsigned w[4];
        #pragma unroll
        for (int j2 = 0; j2 < 4; ++j2) {
            const int c = ch * 32 + quad * 8 + 2 * j2;
            w[j2] = pk2(qkv_w[o * 64 + c] * s, qkv_w[o * 64 + c + 1] * s);
        }
        *(uint4*)&W[WS_WFRAG + (ot * 2 + ch) * 256 + lane * 4] = make_uint4(w[0], w[1], w[2], w[3]);
    } else if (jid < 4672) {               // awfrag
        const int e = jid - 4160;
        const int ot = e >> 7, ch = (e >> 6) & 1, lane = e & 63;
        const int col = lane & 15, quad = lane >> 4;
        const int o = ot * 16 + col;
        const float sc = bn_g[o] * rsqrtf(bn_v[o] + EPS);
        unsigned w[4];
        #pragma unroll
        for (int j2 = 0; j2 < 4; ++j2) {
            const int c = ch * 32 + quad * 8 + 2 * j2;
            w[j2] = pk2(attn_w[o * 64 + c] * sc, attn_w[o * 64 + c + 1] * sc);
        }
        *(uint4*)&W[WS_AWF + (ot * 2 + ch) * 256 + lane * 4] = make_uint4(w[0], w[1], w[2], w[3]);
    } else if (jid < 4864) {               // qb2
        const int o = jid - 4672;
        ((float*)(W + WS_QB2))[o] = qkv_b[o] * ((o < 64) ? 0.25f * LOG2E : 1.f);
    } else if (jid < 4928) {               // aoff
        const int o = jid - 4864;
        const float sc = bn_g[o] * rsqrtf(bn_v[o] + EPS);
        ((float*)(W + WS_AOFF))[o] = attn_b[o] * sc + bn_b[o] - bn_m[o] * sc;
    } else if (jid < 4992) {               // scO
        const int o = jid - 4928;
        ((float*)(W + WS_SCO))[o] = bn_g[o] * rsqrtf(bn_v[o] + EPS);
    } else if (jid < 6592) {               // data_bn sc/sh per (c*25+v)
        const int e = jid - 4992;
        const float sc = dbn_g[e] * rsqrtf(dbn_v[e] + EPS);
        const float sh = dbn_b[e] - dbn_m[e] * sc;
        ((float2*)(W + WS_SCSH))[e] = make_float2(sc, sh);
    }
}

// ---------------------------------------------------------------------------
// k_qkv (MFMA): per (t-tile, n, v-group-of-5). 1520 blocks x 256 thr.
// LDS 10.3 KB -> high occupancy. Waves own ot-groups (3 ot each).
// ---------------------------------------------------------------------------
__global__ __launch_bounds__(256) void k_qkv(
        const float* __restrict__ x, unsigned* __restrict__ W)
{
    const int tt = blockIdx.x, n = blockIdx.y, vg = blockIdx.z, t0 = tt * 16;
    const int tid = threadIdx.x;
    const float2* scsh = (const float2*)(W + WS_SCSH);
    const unsigned* wfrag = W + WS_WFRAG;
    const float* qb2 = (const float*)(W + WS_QB2);
    unsigned* qk_p = W + WS_QK;
    unsigned* v_p  = W + WS_V;

    __shared__ unsigned afrag[5 * 516];    // 10.3 KB

    for (int i = tid; i < 2560; i += 256) {
        const int vloc = i % 5, rest = i / 5;
        const int tcol = rest & 15, pc = rest >> 4;
        const int ch = pc >> 4, quad4 = (pc >> 2) & 3, j2 = pc & 3;
        const int c0 = pc * 2;
        const int v = vg * 5 + vloc;
        const int t = t0 + tcol;
        float a0 = 0.f, a1 = 0.f;
        if (t < TT) {
            const size_t base = ((size_t)(n * 64 + c0) * TT + t) * 25 + v;
            const float2 s0 = scsh[c0 * 25 + v];
            const float2 s1 = scsh[c0 * 25 + 25 + v];
            a0 = fmaf(x[base], s0.x, s0.y);
            a1 = fmaf(x[base + 7500], s1.x, s1.y);
        }
        afrag[vloc * 516 + (ch * 64 + quad4 * 16 + tcol) * 4 + j2] = pk2(a0, a1);
    }
    __syncthreads();

    const int wv = tid >> 6, lane = tid & 63, col = lane & 15, quad = lane >> 4;
    const float4v zero4 = {0.f, 0.f, 0.f, 0.f};

    U8 bf[3][2]; float qb_l[3];
    #pragma unroll
    for (int i = 0; i < 3; ++i) {
        const int ot = 3 * wv + i;
        #pragma unroll
        for (int ch = 0; ch < 2; ++ch) {
            const uint4 u = *(const uint4*)&wfrag[(ot * 2 + ch) * 256 + lane * 4];
            bf[i][ch].w[0] = u.x; bf[i][ch].w[1] = u.y; bf[i][ch].w[2] = u.z; bf[i][ch].w[3] = u.w;
        }
        qb_l[i] = qb2[ot * 16 + col];
    }
    const bool tvalid = (t0 + 4 * quad + 3 < TT);

    for (int vloc = 0; vloc < 5; ++vloc) {
        const int b = n * 25 + vg * 5 + vloc;
        U8 a0, a1;
        { const uint4 u = *(const uint4*)&afrag[vloc * 516 + lane * 4];
          a0.w[0] = u.x; a0.w[1] = u.y; a0.w[2] = u.z; a0.w[3] = u.w; }
        { const uint4 u = *(const uint4*)&afrag[vloc * 516 + 256 + lane * 4];
          a1.w[0] = u.x; a1.w[1] = u.y; a1.w[2] = u.z; a1.w[3] = u.w; }
        #pragma unroll
        for (int i = 0; i < 3; ++i) {
            const int ot = 3 * wv + i;
            float4v acc = __builtin_amdgcn_mfma_f32_16x16x32_bf16(a0.v, bf[i][0].v, zero4, 0, 0, 0);
            acc = __builtin_amdgcn_mfma_f32_16x16x32_bf16(a1.v, bf[i][1].v, acc, 0, 0, 0);
            float val[4];
            #pragma unroll
            for (int r = 0; r < 4; ++r) val[r] = acc[r] + qb_l[i];
            if (ot < 8) {                  // q|k: pair neighbor o lanes
                unsigned pk[4];
                #pragma unroll
                for (int r = 0; r < 4; ++r) {
                    const float p = __shfl_xor(val[r], 1);
                    pk[r] = pk2(val[r], p);
                }
                if (((col & 1) == 0) && tvalid) {
                    const int op = ot * 8 + (col >> 1);
                    *(uint4*)&qk_p[(size_t)(b * 64 + op) * TT + t0 + 4 * quad] =
                        make_uint4(pk[0], pk[1], pk[2], pk[3]);
                }
            } else {                       // v: pair along t; zero-fill t>=300
                const int d = (ot - 8) * 16 + col;
                uint2 u;
                if (tvalid) { u.x = pk2(val[0], val[1]); u.y = pk2(val[2], val[3]); }
                else        { u.x = 0u; u.y = 0u; }
                *(uint2*)&v_p[(size_t)(b * 64 + d) * 152 + 8 * tt + 2 * quad] = u;
            }
        }
    }
}

// ---------------------------------------------------------------------------
// k_attn: per (b, h, t-half). 3200 blocks x 256 thr. Software-pipelined:
// rel ring pre-filled 4 tiles; each 2-stile chunk produces tiles for the
// NEXT chunk (relfrag uint4s prefetched one chunk further). Main loop has
// no validity masks (sts 0..17); st=18 tail specialized. exp2f (log2e
// pre-folded into q).
// ---------------------------------------------------------------------------
__global__ __launch_bounds__(256) void k_attn(unsigned* __restrict__ W)
{
    const int bh = blockIdx.x;             // 0..1599
    const int half = blockIdx.y;           // t-range half
    const int b = bh >> 2, h = bh & 3;
    const int tid  = threadIdx.x;
    const int wave = tid >> 6, lane = tid & 63;
    const int col  = lane & 15, quad = lane >> 4;

    const unsigned* qk_p = W + WS_QK;
    const unsigned* v_p  = W + WS_V;
    unsigned* ah_p = W + WS_AH;
    const unsigned* relfrag = W + WS_REL;

    __shared__ unsigned kbuf[19 * 32 * 4];   // 9.7 KB
    __shared__ unsigned vbuf[10 * 64 * 4];   // 10.2 KB
    __shared__ float relbuf[4][16 * 68];     // [t][m-ring+dup], 17.4 KB
    __shared__ float sbuf[4][16];

    for (int p = tid; p < 2432; p += 256) {
        const int c = p & 15, j2 = (p >> 4) & 3, qh = (p >> 6) & 1, st = p >> 7;
        kbuf[(st * 32 + qh * 16 + c) * 4 + j2] =
            qk_p[(size_t)(b * 64 + 32 + h * 8 + qh * 4 + j2) * TT + st * 16 + c];
    }
    for (int p = tid; p < 640; p += 256) {
        const int tq = p % 40, c = p / 40;
        const uint4 u = *(const uint4*)&v_p[(size_t)(b * 64 + h * 16 + c) * 152 + tq * 4];
        *(uint4*)&vbuf[((tq >> 2) * 64 + (tq & 3) * 16 + c) * 4] = u;
    }
    __syncthreads();

    float* relw = &relbuf[wave][0];
    const float4v zero4 = {0.f, 0.f, 0.f, 0.f};
    const int lA = ((2 * quad) & 3) * 16 + col;
    const int lB = ((2 * quad + 1) & 3) * 16 + col;

    const int ttlo = half ? 10 : 0;
    const int tthi = half ? 19 : 10;

    for (int tt = ttlo + wave; tt < tthi; tt += 4) {
        const int t0 = tt * 16;

        // ---- Q B-frag (cols = t) ----
        U8 qf;
        if (quad < 2) {
            int t = t0 + col; if (t > TT - 1) t = TT - 1;
            const size_t rb = (size_t)(b * 64 + h * 8 + quad * 4) * TT + t;
            qf.w[0] = qk_p[rb];
            qf.w[1] = qk_p[rb + TT];
            qf.w[2] = qk_p[rb + 2 * TT];
            qf.w[3] = qk_p[rb + 3 * TT];
        } else {
            qf.w[0] = qf.w[1] = qf.w[2] = qf.w[3] = 0u;
        }

        auto rel_ld = [&](int mt) -> uint4 {
            return *(const uint4*)&relfrag[(mt + 1) * 256 + lane * 4];
        };
        auto rel_do = [&](int mt, uint4 u) {
            U8 kr; kr.w[0] = u.x; kr.w[1] = u.y; kr.w[2] = u.z; kr.w[3] = u.w;
            const float4v rc = __builtin_amdgcn_mfma_f32_16x16x32_bf16(
                                   kr.v, qf.v, zero4, 0, 0, 0);
            const float4 s4 = make_float4(rc[0], rc[1], rc[2], rc[3]);
            *(float4*)&relw[col * 68 + ((mt & 3) * 16 + quad * 4)] = s4;
            if (((mt & 3) == 0) && (quad == 0))
                *(float4*)&relw[col * 68 + 64] = s4;
        };

        // prologue: fill ring with tiles (17-tt)..(20-tt); prefetch 21,22
        #pragma unroll
        for (int i = 0; i < 4; ++i) rel_do(17 - tt + i, rel_ld(17 - tt + i));
        uint4 ru0 = rel_ld(21 - tt), ru1 = rel_ld(22 - tt);

        float4v accPV = zero4;
        float sumA = 0.f;
        const int mbb = 4 * quad - t0 - col + (TT - 1);

        #pragma unroll 1
        for (int c = 0; c < 9; ++c) {       // sts 0..17, no masks needed
            U8 kf0, kf1;
            if (quad < 2) {
                const uint4 u0 = *(const uint4*)&kbuf[((2 * c) * 32 + quad * 16 + col) * 4];
                const uint4 u1 = *(const uint4*)&kbuf[((2 * c + 1) * 32 + quad * 16 + col) * 4];
                kf0.w[0] = u0.x; kf0.w[1] = u0.y; kf0.w[2] = u0.z; kf0.w[3] = u0.w;
                kf1.w[0] = u1.x; kf1.w[1] = u1.y; kf1.w[2] = u1.z; kf1.w[3] = u1.w;
            } else {
                kf0.w[0] = kf0.w[1] = kf0.w[2] = kf0.w[3] = 0u;
                kf1.w[0] = kf1.w[1] = kf1.w[2] = kf1.w[3] = 0u;
            }
            const float4v qk0 = __builtin_amdgcn_mfma_f32_16x16x32_bf16(kf0.v, qf.v, zero4, 0, 0, 0);
            const float4v qk1 = __builtin_amdgcn_mfma_f32_16x16x32_bf16(kf1.v, qf.v, zero4, 0, 0, 0);

            const int mb0 = 32 * c + mbb;
            const float* rp0 = &relw[col * 68 + (mb0 & 63)];
            const float* rp1 = &relw[col * 68 + ((mb0 + 16) & 63)];
            const float e0 = exp2f(qk0[0] + rp0[0]);
            const float e1 = exp2f(qk0[1] + rp0[1]);
            const float e2 = exp2f(qk0[2] + rp0[2]);
            const float e3 = exp2f(qk0[3] + rp0[3]);
            const float e4 = exp2f(qk1[0] + rp1[0]);
            const float e5 = exp2f(qk1[1] + rp1[1]);
            const float e6 = exp2f(qk1[2] + rp1[2]);
            const float e7 = exp2f(qk1[3] + rp1[3]);
            sumA += ((e0 + e1) + (e2 + e3)) + ((e4 + e5) + (e6 + e7));

            const unsigned q0 = pk2(e0, e1), q1 = pk2(e2, e3);
            const unsigned q2 = pk2(e4, e5), q3 = pk2(e6, e7);
            const unsigned a0 = (unsigned)__shfl((int)q0, lA, 64);
            const unsigned b0 = (unsigned)__shfl((int)q2, lA, 64);
            const unsigned a1 = (unsigned)__shfl((int)q1, lA, 64);
            const unsigned b1 = (unsigned)__shfl((int)q3, lA, 64);
            const unsigned a2 = (unsigned)__shfl((int)q0, lB, 64);
            const unsigned b2 = (unsigned)__shfl((int)q2, lB, 64);
            const unsigned a3 = (unsigned)__shfl((int)q1, lB, 64);
            const unsigned b3 = (unsigned)__shfl((int)q3, lB, 64);
            U8 pf;
            pf.w[0] = (quad < 2) ? a0 : b0;
            pf.w[1] = (quad < 2) ? a1 : b1;
            pf.w[2] = (quad < 2) ? a2 : b2;
            pf.w[3] = (quad < 2) ? a3 : b3;
            const short8 vf = *(const short8*)&vbuf[(c * 64 + lane) * 4];
            accPV = __builtin_amdgcn_mfma_f32_16x16x32_bf16(pf.v, vf, accPV, 0, 0, 0);

            // produce rel tiles for NEXT chunk; prefetch one further
            rel_do(2 * c + 21 - tt, ru0);
            rel_do(2 * c + 22 - tt, ru1);
            if (c < 8) { ru0 = rel_ld(2 * c + 23 - tt); ru1 = rel_ld(2 * c + 24 - tt); }
        }

        // ---- tail: st = 18 (s 288..303; s>=300 masked) ----
        {
            U8 kf0;
            if (quad < 2) {
                const uint4 u0 = *(const uint4*)&kbuf[(18 * 32 + quad * 16 + col) * 4];
                kf0.w[0] = u0.x; kf0.w[1] = u0.y; kf0.w[2] = u0.z; kf0.w[3] = u0.w;
            } else {
                kf0.w[0] = kf0.w[1] = kf0.w[2] = kf0.w[3] = 0u;
            }
            const float4v qk0 = __builtin_amdgcn_mfma_f32_16x16x32_bf16(kf0.v, qf.v, zero4, 0, 0, 0);
            const int mb0 = 288 + mbb;
            const float* rp0 = &relw[col * 68 + (mb0 & 63)];
            float e0 = exp2f(qk0[0] + rp0[0]);
            float e1 = exp2f(qk0[1] + rp0[1]);
            float e2 = exp2f(qk0[2] + rp0[2]);
            float e3 = exp2f(qk0[3] + rp0[3]);
            if (quad == 3) { e0 = e1 = e2 = e3 = 0.f; }
            sumA += (e0 + e1) + (e2 + e3);
            const unsigned q0 = pk2(e0, e1), q1 = pk2(e2, e3);
            const unsigned a0 = (unsigned)__shfl((int)q0, lA, 64);
            const unsigned a1 = (unsigned)__shfl((int)q1, lA, 64);
            const unsigned a2 = (unsigned)__shfl((int)q0, lB, 64);
            const unsigned a3 = (unsigned)__shfl((int)q1, lB, 64);
            U8 pf;
            pf.w[0] = (quad < 2) ? a0 : 0u;
            pf.w[1] = (quad < 2) ? a1 : 0u;
            pf.w[2] = (quad < 2) ? a2 : 0u;
            pf.w[3] = (quad < 2) ? a3 : 0u;
            const short8 vf = *(const short8*)&vbuf[(9 * 64 + lane) * 4];
            accPV = __builtin_amdgcn_mfma_f32_16x16x32_bf16(pf.v, vf, accPV, 0, 0, 0);
        }

        // ---- finalize: row sums, normalize, bf16 t-paired store ----
        sumA += __shfl_xor(sumA, 16, 64);
        sumA += __shfl_xor(sumA, 32, 64);
        if (lane < 16) sbuf[wave][lane] = sumA;
        const float4 rs = *(const float4*)&sbuf[wave][4 * quad];
        if (t0 + 4 * quad + 3 < TT) {
            uint2 u;
            u.x = pk2(accPV[0] / rs.x, accPV[1] / rs.y);
            u.y = pk2(accPV[2] / rs.z, accPV[3] / rs.w);
            *(uint2*)&ah_p[(size_t)(b * 64 + h * 16 + col) * 152 + 8 * tt + 2 * quad] = u;
        }
    }
}

// ---------------------------------------------------------------------------
// k_out (MFMA): per (t-tile, n, t-quarter). 4 t per block, 16 KB LDS,
// 1216 blocks.
// ---------------------------------------------------------------------------
__global__ __launch_bounds__(256) void k_out(
        const float* __restrict__ x, const unsigned* __restrict__ W,
        float* __restrict__ out)
{
    const int tt = blockIdx.x, n = blockIdx.y, tq = blockIdx.z;
    if (tt == 18 && tq == 3) return;
    const int t0 = tt * 16;
    const int tid = threadIdx.x;
    const unsigned* ah_p = W + WS_AH;
    const unsigned* awfrag = W + WS_AWF;
    const float* aoff = (const float*)(W + WS_AOFF);
    const float* scO  = (const float*)(W + WS_SCO);

    __shared__ unsigned fbuf[4 * 1024];    // 16 KB, +12t swizzle, col^quad

    for (int i = tid; i < 1600; i += 256) {
        const int tp2 = i & 1, pc = (i >> 1) & 31, v = i >> 6;
        const int b = n * 25 + v;
        const size_t r0 = (size_t)(b * 64 + 2 * pc) * 152 + tt * 8 + tq * 2 + tp2;
        const unsigned A = ah_p[r0], Bv = ah_p[r0 + 152];
        const unsigned ue = (A & 0xFFFFu) | (Bv << 16);
        const unsigned uo = (A >> 16) | (Bv & 0xFFFF0000u);
        const int vt = v >> 4, cv = v & 15, ch = pc >> 4, qd = (pc >> 2) & 3, j2 = pc & 3;
        const int xi = (vt * 2 + ch) * 256 + (qd * 16 + (cv ^ qd)) * 4 + j2;
        const int tl = 2 * tp2;
        fbuf[tl * 1024 + ((xi + 12 * tl) & 1023)]             = ue;
        fbuf[(tl + 1) * 1024 + ((xi + 12 * (tl + 1)) & 1023)] = uo;
    }
    __syncthreads();

    const int wv = tid >> 6, lane = tid & 63, col = lane & 15, quad = lane >> 4;
    const int o = wv * 16 + col;
    const float4v zero4 = {0.f, 0.f, 0.f, 0.f};

    U8 awf0, awf1;
    { const uint4 u = *(const uint4*)&awfrag[(wv * 2 + 0) * 256 + lane * 4];
      awf0.w[0] = u.x; awf0.w[1] = u.y; awf0.w[2] = u.z; awf0.w[3] = u.w; }
    { const uint4 u = *(const uint4*)&awfrag[(wv * 2 + 1) * 256 + lane * 4];
      awf1.w[0] = u.x; awf1.w[1] = u.y; awf1.w[2] = u.z; awf1.w[3] = u.w; }
    const float aoff_l = aoff[o], sc_l = scO[o];

    for (int tl = 0; tl < 4; ++tl) {
        const int t = t0 + 4 * tq + tl;
        #pragma unroll
        for (int vt = 0; vt < 2; ++vt) {
            U8 a0, a1;
            { const int xb = (vt * 2 + 0) * 256 + (quad * 16 + (col ^ quad)) * 4;
              const uint4 u = *(const uint4*)&fbuf[tl * 1024 + ((xb + 12 * tl) & 1023)];
              a0.w[0] = u.x; a0.w[1] = u.y; a0.w[2] = u.z; a0.w[3] = u.w; }
            { const int xb = (vt * 2 + 1) * 256 + (quad * 16 + (col ^ quad)) * 4;
              const uint4 u = *(const uint4*)&fbuf[tl * 1024 + ((xb + 12 * tl) & 1023)];
              a1.w[0] = u.x; a1.w[1] = u.y; a1.w[2] = u.z; a1.w[3] = u.w; }
            float4v acc = __builtin_amdgcn_mfma_f32_16x16x32_bf16(a0.v, awf0.v, zero4, 0, 0, 0);
            acc = __builtin_amdgcn_mfma_f32_16x16x32_bf16(a1.v, awf1.v, acc, 0, 0, 0);
            #pragma unroll
            for (int r = 0; r < 4; ++r) {
                const int v = vt * 16 + 4 * quad + r;
                if (v < 25) {
                    const size_t xidx = ((size_t)(n * 64 + o) * TT + t) * 25 + v;
                    const float val = acc[r] + x[xidx] * sc_l + aoff_l;
                    out[xidx] = fmaxf(val, 0.f);
                }
            }
        }
    }
}

// ---------------------------------------------------------------------------
extern "C" void kernel_launch(void* const* d_in, const int* in_sizes, int n_in,
                              void* d_out, int out_size, void* d_ws, size_t ws_size,
                              hipStream_t stream)
{
    const float* x       = (const float*)d_in[0];
    const float* dbn_g   = (const float*)d_in[1];
    const float* dbn_b   = (const float*)d_in[2];
    const float* dbn_m   = (const float*)d_in[3];
    const float* dbn_v   = (const float*)d_in[4];
    const float* qkv_w   = (const float*)d_in[5];
    const float* qkv_b   = (const float*)d_in[6];
    const float* key_rel = (const float*)d_in[7];
    const float* attn_w  = (const float*)d_in[8];
    const float* attn_b  = (const float*)d_in[9];
    const float* bn_g    = (const float*)d_in[10];
    const float* bn_b    = (const float*)d_in[11];
    const float* bn_m    = (const float*)d_in[12];
    const float* bn_v    = (const float*)d_in[13];
    float* out = (float*)d_out;
    unsigned* W = (unsigned*)d_ws;

    k_pre<<<26, 256, 0, stream>>>(dbn_g, dbn_b, dbn_m, dbn_v, qkv_w, qkv_b,
                                  key_rel, attn_w, attn_b, bn_g, bn_b, bn_m,
                                  bn_v, W);
    k_qkv<<<dim3(19, 16, 5), 256, 0, stream>>>(x, W);
    k_attn<<<dim3(1600, 2), 256, 0, stream>>>(W);
    k_out<<<dim3(19, 16, 4), 256, 0, stream>>>(x, W, out);
}

// Round 6
// 264.863 us; speedup vs baseline: 7.0873x; 1.0711x over previous
//
#include <hip/hip_runtime.h>
#include <hip/hip_bf16.h>
#include <cstddef>

// Problem constants
#define NN 16
#define CC 64
#define TT 300
#define VV 25
#define NHH 4
#define DKHH 16
#define BB (NN * VV)          // 400
#define EPS 1e-5f
#define LOG2E 1.4426950408889634f

// Workspace layout (u32 units)
#define WS_QK    0            // u32[400][64][300]  q|k bf16, paired along o (q pre-scaled 0.25*log2e)
#define WS_V     7680000      // u32[400][64][152]  v bf16, paired along t (t>=300 zero-filled)
#define WS_AH    11571200     // u32[400][64][152]  attnh bf16, paired along t
#define WS_REL   15462400     // u32[41][64][4] key_rel frags (slot = mtile+1, slot0 = zeros)
#define WS_AWF   15472896     // u32[4][2][64][4] attn_w B-frags (pre-scaled by bn scale)
#define WS_AOFF  15474944     // f32[64] fused attn_b+bn offset
#define WS_SCO   15475008     // f32[64] bn scale (for skip path)
#define WS_QBV   15475072     // f32[25][192] fused qkv bias (bn shift folded, q pre-scaled)
#define WS_WV    15479872     // u32[25][12][2][64][4] per-v qkv_w B-frags (bn scale folded)

typedef __attribute__((ext_vector_type(8))) short short8;
typedef __attribute__((ext_vector_type(4))) float float4v;

union U8 { short8 v; unsigned int w[4]; };

// f32x2 -> packed bf16x2 (RNE). HW op if available, else manual.
__device__ __forceinline__ unsigned int pk2(float a, float b) {
#if __has_builtin(__builtin_amdgcn_cvt_pk_bf16_f32)
    typedef __attribute__((ext_vector_type(2))) __bf16 bf2;
    union { bf2 v; unsigned u; } c;
    c.v = __builtin_amdgcn_cvt_pk_bf16_f32(a, b);
    return c.u;
#else
    union { float f; unsigned u; } x, y;
    x.f = a; y.f = b;
    unsigned ua = x.u + 0x7FFFu + ((x.u >> 16) & 1u);
    unsigned ub = y.u + 0x7FFFu + ((y.u >> 16) & 1u);
    return (ua >> 16) | (ub & 0xFFFF0000u);
#endif
}

__device__ __forceinline__ float ex2(float x) {
#if __has_builtin(__builtin_amdgcn_exp2f)
    return __builtin_amdgcn_exp2f(x);
#else
    return exp2f(x);
#endif
}

__device__ __forceinline__ float rcpf_(float x) {
#if __has_builtin(__builtin_amdgcn_rcpf)
    return __builtin_amdgcn_rcpf(x);
#else
    return 1.f / x;
#endif
}

// ---------------------------------------------------------------------------
// k_pre: constant tables. New: per-v qkv weight frags with data_bn scale
// folded in (wv) and fused bias qbv[v][o] = qs*(qkv_b[o] + sum_c w[o,c]*sh[c,v]).
// ---------------------------------------------------------------------------
__global__ __launch_bounds__(256) void k_pre(
    const float* __restrict__ dbn_g, const float* __restrict__ dbn_b,
    const float* __restrict__ dbn_m, const float* __restrict__ dbn_v,
    const float* __restrict__ qkv_w, const float* __restrict__ qkv_b,
    const float* __restrict__ key_rel,
    const float* __restrict__ attn_w, const float* __restrict__ attn_b,
    const float* __restrict__ bn_g, const float* __restrict__ bn_b,
    const float* __restrict__ bn_m, const float* __restrict__ bn_v,
    unsigned* __restrict__ W)
{
    const int jid = blockIdx.x * 256 + threadIdx.x;
    if (jid < 2624) {                      // relfrag: 41 slots x 64 lanes
        const int k = jid >> 6, lane = jid & 63, col = lane & 15, quad = lane >> 4;
        const int mt = k - 1, m = mt * 16 + col;
        const bool ok = (quad < 2) && (mt >= 0) && (m < 2 * TT - 1);
        unsigned w[4];
        #pragma unroll
        for (int j2 = 0; j2 < 4; ++j2) {
            const int c = quad * 8 + 2 * j2;
            const float v0 = ok ? key_rel[m * 16 + c] : 0.f;
            const float v1 = ok ? key_rel[m * 16 + c + 1] : 0.f;
            w[j2] = pk2(v0, v1);
        }
        *(uint4*)&W[WS_REL + k * 256 + lane * 4] = make_uint4(w[0], w[1], w[2], w[3]);
    } else if (jid < 3136) {               // awfrag: 4 otiles x 2 chalf x 64
        const int e = jid - 2624;
        const int ot = e >> 7, ch = (e >> 6) & 1, lane = e & 63;
        const int col = lane & 15, quad = lane >> 4;
        const int o = ot * 16 + col;
        const float sc = bn_g[o] * rsqrtf(bn_v[o] + EPS);
        unsigned w[4];
        #pragma unroll
        for (int j2 = 0; j2 < 4; ++j2) {
            const int c = ch * 32 + quad * 8 + 2 * j2;
            w[j2] = pk2(attn_w[o * 64 + c] * sc, attn_w[o * 64 + c + 1] * sc);
        }
        *(uint4*)&W[WS_AWF + (ot * 2 + ch) * 256 + lane * 4] = make_uint4(w[0], w[1], w[2], w[3]);
    } else if (jid < 3200) {               // aoff
        const int o = jid - 3136;
        const float sc = bn_g[o] * rsqrtf(bn_v[o] + EPS);
        ((float*)(W + WS_AOFF))[o] = attn_b[o] * sc + bn_b[o] - bn_m[o] * sc;
    } else if (jid < 3264) {               // scO
        const int o = jid - 3200;
        ((float*)(W + WS_SCO))[o] = bn_g[o] * rsqrtf(bn_v[o] + EPS);
    } else if (jid < 8064) {               // qbv: 25 v x 192 o
        const int e = jid - 3264;
        const int v = e / 192, o = e - 192 * v;
        const float qs = (o < 64) ? 0.25f * LOG2E : 1.f;
        float acc = qkv_b[o];
        for (int c = 0; c < 64; ++c) {
            const int ch = c * 25 + v;
            const float sc = dbn_g[ch] * rsqrtf(dbn_v[ch] + EPS);
            const float sh = dbn_b[ch] - dbn_m[ch] * sc;
            acc += qkv_w[o * 64 + c] * sh;
        }
        ((float*)(W + WS_QBV))[v * 192 + o] = acc * qs;
    } else if (jid < 46464) {              // wv: 25 v x 12 ot x 2 ch x 64 lanes
        const int e = jid - 8064;
        const int v = e / 1536, r = e - 1536 * v;
        const int ot = r >> 7, ch = (r >> 6) & 1, lane = r & 63;
        const int col = lane & 15, quad = lane >> 4;
        const int o = ot * 16 + col;
        const float qs = (o < 64) ? 0.25f * LOG2E : 1.f;
        unsigned w[4];
        #pragma unroll
        for (int j2 = 0; j2 < 4; ++j2) {
            const int c = ch * 32 + quad * 8 + 2 * j2;
            const float sc0 = dbn_g[c * 25 + v] * rsqrtf(dbn_v[c * 25 + v] + EPS);
            const float sc1 = dbn_g[(c + 1) * 25 + v] * rsqrtf(dbn_v[(c + 1) * 25 + v] + EPS);
            w[j2] = pk2(qkv_w[o * 64 + c] * qs * sc0, qkv_w[o * 64 + c + 1] * qs * sc1);
        }
        *(uint4*)&W[WS_WV + ((v * 12 + ot) * 2 + ch) * 256 + lane * 4] =
            make_uint4(w[0], w[1], w[2], w[3]);
    }
}

// ---------------------------------------------------------------------------
// k_qkv (MFMA): per (t-tile, n), 512 thr. x staged as float4 from contiguous
// 1600 B runs (raw x, bn folded into per-v weights). 8 waves = (otg, vhalf).
// ---------------------------------------------------------------------------
__global__ __launch_bounds__(512) void k_qkv(
        const float* __restrict__ x, unsigned* __restrict__ W)
{
    const int tt = blockIdx.x, n = blockIdx.y, t0 = tt * 16;
    const int tid = threadIdx.x;
    const unsigned* wv = W + WS_WV;
    const float* qbv = (const float*)(W + WS_QBV);
    unsigned* qk_p = W + WS_QK;
    unsigned* v_p  = W + WS_V;

    __shared__ unsigned afrag[25 * 516];   // 51.6 KB

    // stage: 3200 jobs = 32 c-pairs x 100 float4 (contiguous flat = t*25+v)
    for (int i = tid; i < 3200; i += 512) {
        const int f4 = i % 100, cp = i / 100;
        const int c0 = cp * 2;
        float4 xa = make_float4(0.f, 0.f, 0.f, 0.f);
        float4 xb = make_float4(0.f, 0.f, 0.f, 0.f);
        if (tt < 18 || f4 < 75) {          // tail tile: only 300 floats valid
            const float* p = x + (size_t)(n * 64 + c0) * 7500 + tt * 400 + f4 * 4;
            xa = *(const float4*)p;
            xb = *(const float4*)(p + 7500);
        }
        const int ch = cp >> 4, qd = (cp >> 2) & 3, j2 = cp & 3;
        const float ea[4] = {xa.x, xa.y, xa.z, xa.w};
        const float eb[4] = {xb.x, xb.y, xb.z, xb.w};
        #pragma unroll
        for (int e = 0; e < 4; ++e) {
            const int flat = f4 * 4 + e;
            const int tl = (flat * 5243) >> 17;     // flat / 25
            const int v  = flat - 25 * tl;
            afrag[v * 516 + (ch * 64 + qd * 16 + tl) * 4 + j2] = pk2(ea[e], eb[e]);
        }
    }
    __syncthreads();

    const int wvv = tid >> 6, lane = tid & 63, col = lane & 15, quad = lane >> 4;
    const int otg = wvv >> 1, vh = wvv & 1;
    const int vlo = 13 * vh, vhi = vh ? 25 : 13;
    const float4v zero4 = {0.f, 0.f, 0.f, 0.f};
    const bool tvalid = (t0 + 4 * quad + 3 < TT);

    for (int v = vlo; v < vhi; ++v) {
        const int b = n * 25 + v;
        U8 a0, a1;
        { const uint4 u = *(const uint4*)&afrag[v * 516 + lane * 4];
          a0.w[0] = u.x; a0.w[1] = u.y; a0.w[2] = u.z; a0.w[3] = u.w; }
        { const uint4 u = *(const uint4*)&afrag[v * 516 + 256 + lane * 4];
          a1.w[0] = u.x; a1.w[1] = u.y; a1.w[2] = u.z; a1.w[3] = u.w; }
        #pragma unroll
        for (int i = 0; i < 3; ++i) {
            const int ot = 3 * otg + i;
            U8 b0, b1;
            { const uint4 u = *(const uint4*)&wv[((v * 12 + ot) * 2 + 0) * 256 + lane * 4];
              b0.w[0] = u.x; b0.w[1] = u.y; b0.w[2] = u.z; b0.w[3] = u.w; }
            { const uint4 u = *(const uint4*)&wv[((v * 12 + ot) * 2 + 1) * 256 + lane * 4];
              b1.w[0] = u.x; b1.w[1] = u.y; b1.w[2] = u.z; b1.w[3] = u.w; }
            const float qb = qbv[v * 192 + ot * 16 + col];
            float4v acc = __builtin_amdgcn_mfma_f32_16x16x32_bf16(a0.v, b0.v, zero4, 0, 0, 0);
            acc = __builtin_amdgcn_mfma_f32_16x16x32_bf16(a1.v, b1.v, acc, 0, 0, 0);
            float val[4];
            #pragma unroll
            for (int r = 0; r < 4; ++r) val[r] = acc[r] + qb;
            if (ot < 8) {                  // q|k: pair neighbor o lanes
                unsigned pk[4];
                #pragma unroll
                for (int r = 0; r < 4; ++r) {
                    const float p = __shfl_xor(val[r], 1);
                    pk[r] = pk2(val[r], p);
                }
                if (((col & 1) == 0) && tvalid) {
                    const int op = ot * 8 + (col >> 1);
                    *(uint4*)&qk_p[(size_t)(b * 64 + op) * TT + t0 + 4 * quad] =
                        make_uint4(pk[0], pk[1], pk[2], pk[3]);
                }
            } else {                       // v: pair along t; zero-fill t>=300
                const int d = (ot - 8) * 16 + col;
                uint2 u;
                if (tvalid) { u.x = pk2(val[0], val[1]); u.y = pk2(val[2], val[3]); }
                else        { u.x = 0u; u.y = 0u; }
                *(uint2*)&v_p[(size_t)(b * 64 + d) * 152 + 8 * tt + 2 * quad] = u;
            }
        }
    }
}

// ---------------------------------------------------------------------------
// k_attn: per (b, h, t-half). 3200 blocks x 256 thr. (unchanged structure
// from R5; exp2/rcp via builtins, WS_REL offset updated)
// ---------------------------------------------------------------------------
__global__ __launch_bounds__(256) void k_attn(unsigned* __restrict__ W)
{
    const int bh = blockIdx.x;             // 0..1599
    const int half = blockIdx.y;           // t-range half
    const int b = bh >> 2, h = bh & 3;
    const int tid  = threadIdx.x;
    const int wave = tid >> 6, lane = tid & 63;
    const int col  = lane & 15, quad = lane >> 4;

    const unsigned* qk_p = W + WS_QK;
    const unsigned* v_p  = W + WS_V;
    unsigned* ah_p = W + WS_AH;
    const unsigned* relfrag = W + WS_REL;

    __shared__ unsigned kbuf[19 * 32 * 4];   // 9.7 KB
    __shared__ unsigned vbuf[10 * 64 * 4];   // 10.2 KB
    __shared__ float relbuf[4][16 * 68];     // [t][m-ring+dup], 17.4 KB
    __shared__ float sbuf[4][16];

    for (int p = tid; p < 2432; p += 256) {
        const int c = p & 15, j2 = (p >> 4) & 3, qh = (p >> 6) & 1, st = p >> 7;
        kbuf[(st * 32 + qh * 16 + c) * 4 + j2] =
            qk_p[(size_t)(b * 64 + 32 + h * 8 + qh * 4 + j2) * TT + st * 16 + c];
    }
    for (int p = tid; p < 640; p += 256) {
        const int tq = p % 40, c = p / 40;
        const uint4 u = *(const uint4*)&v_p[(size_t)(b * 64 + h * 16 + c) * 152 + tq * 4];
        *(uint4*)&vbuf[((tq >> 2) * 64 + (tq & 3) * 16 + c) * 4] = u;
    }
    __syncthreads();

    float* relw = &relbuf[wave][0];
    const float4v zero4 = {0.f, 0.f, 0.f, 0.f};
    const int lA = ((2 * quad) & 3) * 16 + col;
    const int lB = ((2 * quad + 1) & 3) * 16 + col;

    const int ttlo = half ? 10 : 0;
    const int tthi = half ? 19 : 10;

    for (int tt = ttlo + wave; tt < tthi; tt += 4) {
        const int t0 = tt * 16;

        // ---- Q B-frag (cols = t) ----
        U8 qf;
        if (quad < 2) {
            int t = t0 + col; if (t > TT - 1) t = TT - 1;
            const size_t rb = (size_t)(b * 64 + h * 8 + quad * 4) * TT + t;
            qf.w[0] = qk_p[rb];
            qf.w[1] = qk_p[rb + TT];
            qf.w[2] = qk_p[rb + 2 * TT];
            qf.w[3] = qk_p[rb + 3 * TT];
        } else {
            qf.w[0] = qf.w[1] = qf.w[2] = qf.w[3] = 0u;
        }

        auto rel_ld = [&](int mt) -> uint4 {
            return *(const uint4*)&relfrag[(mt + 1) * 256 + lane * 4];
        };
        auto rel_do = [&](int mt, uint4 u) {
            U8 kr; kr.w[0] = u.x; kr.w[1] = u.y; kr.w[2] = u.z; kr.w[3] = u.w;
            const float4v rc = __builtin_amdgcn_mfma_f32_16x16x32_bf16(
                                   kr.v, qf.v, zero4, 0, 0, 0);
            const float4 s4 = make_float4(rc[0], rc[1], rc[2], rc[3]);
            *(float4*)&relw[col * 68 + ((mt & 3) * 16 + quad * 4)] = s4;
            if (((mt & 3) == 0) && (quad == 0))
                *(float4*)&relw[col * 68 + 64] = s4;
        };

        #pragma unroll
        for (int i = 0; i < 4; ++i) rel_do(17 - tt + i, rel_ld(17 - tt + i));
        uint4 ru0 = rel_ld(21 - tt), ru1 = rel_ld(22 - tt);

        float4v accPV = zero4;
        float sumA = 0.f;
        const int mbb = 4 * quad - t0 - col + (TT - 1);

        #pragma unroll 1
        for (int c = 0; c < 9; ++c) {       // sts 0..17, no masks needed
            U8 kf0, kf1;
            if (quad < 2) {
                const uint4 u0 = *(const uint4*)&kbuf[((2 * c) * 32 + quad * 16 + col) * 4];
                const uint4 u1 = *(const uint4*)&kbuf[((2 * c + 1) * 32 + quad * 16 + col) * 4];
                kf0.w[0] = u0.x; kf0.w[1] = u0.y; kf0.w[2] = u0.z; kf0.w[3] = u0.w;
                kf1.w[0] = u1.x; kf1.w[1] = u1.y; kf1.w[2] = u1.z; kf1.w[3] = u1.w;
            } else {
                kf0.w[0] = kf0.w[1] = kf0.w[2] = kf0.w[3] = 0u;
                kf1.w[0] = kf1.w[1] = kf1.w[2] = kf1.w[3] = 0u;
            }
            const float4v qk0 = __builtin_amdgcn_mfma_f32_16x16x32_bf16(kf0.v, qf.v, zero4, 0, 0, 0);
            const float4v qk1 = __builtin_amdgcn_mfma_f32_16x16x32_bf16(kf1.v, qf.v, zero4, 0, 0, 0);

            const int mb0 = 32 * c + mbb;
            const float* rp0 = &relw[col * 68 + (mb0 & 63)];
            const float* rp1 = &relw[col * 68 + ((mb0 + 16) & 63)];
            const float e0 = ex2(qk0[0] + rp0[0]);
            const float e1 = ex2(qk0[1] + rp0[1]);
            const float e2 = ex2(qk0[2] + rp0[2]);
            const float e3 = ex2(qk0[3] + rp0[3]);
            const float e4 = ex2(qk1[0] + rp1[0]);
            const float e5 = ex2(qk1[1] + rp1[1]);
            const float e6 = ex2(qk1[2] + rp1[2]);
            const float e7 = ex2(qk1[3] + rp1[3]);
            sumA += ((e0 + e1) + (e2 + e3)) + ((e4 + e5) + (e6 + e7));

            const unsigned q0 = pk2(e0, e1), q1 = pk2(e2, e3);
            const unsigned q2 = pk2(e4, e5), q3 = pk2(e6, e7);
            const unsigned a0 = (unsigned)__shfl((int)q0, lA, 64);
            const unsigned b0 = (unsigned)__shfl((int)q2, lA, 64);
            const unsigned a1 = (unsigned)__shfl((int)q1, lA, 64);
            const unsigned b1 = (unsigned)__shfl((int)q3, lA, 64);
            const unsigned a2 = (unsigned)__shfl((int)q0, lB, 64);
            const unsigned b2 = (unsigned)__shfl((int)q2, lB, 64);
            const unsigned a3 = (unsigned)__shfl((int)q1, lB, 64);
            const unsigned b3 = (unsigned)__shfl((int)q3, lB, 64);
            U8 pf;
            pf.w[0] = (quad < 2) ? a0 : b0;
            pf.w[1] = (quad < 2) ? a1 : b1;
            pf.w[2] = (quad < 2) ? a2 : b2;
            pf.w[3] = (quad < 2) ? a3 : b3;
            const short8 vf = *(const short8*)&vbuf[(c * 64 + lane) * 4];
            accPV = __builtin_amdgcn_mfma_f32_16x16x32_bf16(pf.v, vf, accPV, 0, 0, 0);

            rel_do(2 * c + 21 - tt, ru0);
            rel_do(2 * c + 22 - tt, ru1);
            if (c < 8) { ru0 = rel_ld(2 * c + 23 - tt); ru1 = rel_ld(2 * c + 24 - tt); }
        }

        // ---- tail: st = 18 (s 288..303; s>=300 masked) ----
        {
            U8 kf0;
            if (quad < 2) {
                const uint4 u0 = *(const uint4*)&kbuf[(18 * 32 + quad * 16 + col) * 4];
                kf0.w[0] = u0.x; kf0.w[1] = u0.y; kf0.w[2] = u0.z; kf0.w[3] = u0.w;
            } else {
                kf0.w[0] = kf0.w[1] = kf0.w[2] = kf0.w[3] = 0u;
            }
            const float4v qk0 = __builtin_amdgcn_mfma_f32_16x16x32_bf16(kf0.v, qf.v, zero4, 0, 0, 0);
            const int mb0 = 288 + mbb;
            const float* rp0 = &relw[col * 68 + (mb0 & 63)];
            float e0 = ex2(qk0[0] + rp0[0]);
            float e1 = ex2(qk0[1] + rp0[1]);
            float e2 = ex2(qk0[2] + rp0[2]);
            float e3 = ex2(qk0[3] + rp0[3]);
            if (quad == 3) { e0 = e1 = e2 = e3 = 0.f; }
            sumA += (e0 + e1) + (e2 + e3);
            const unsigned q0 = pk2(e0, e1), q1 = pk2(e2, e3);
            const unsigned a0 = (unsigned)__shfl((int)q0, lA, 64);
            const unsigned a1 = (unsigned)__shfl((int)q1, lA, 64);
            const unsigned a2 = (unsigned)__shfl((int)q0, lB, 64);
            const unsigned a3 = (unsigned)__shfl((int)q1, lB, 64);
            U8 pf;
            pf.w[0] = (quad < 2) ? a0 : 0u;
            pf.w[1] = (quad < 2) ? a1 : 0u;
            pf.w[2] = (quad < 2) ? a2 : 0u;
            pf.w[3] = (quad < 2) ? a3 : 0u;
            const short8 vf = *(const short8*)&vbuf[(9 * 64 + lane) * 4];
            accPV = __builtin_amdgcn_mfma_f32_16x16x32_bf16(pf.v, vf, accPV, 0, 0, 0);
        }

        // ---- finalize: row sums, normalize (rcp), bf16 t-paired store ----
        sumA += __shfl_xor(sumA, 16, 64);
        sumA += __shfl_xor(sumA, 32, 64);
        if (lane < 16) sbuf[wave][lane] = sumA;
        const float4 rs = *(const float4*)&sbuf[wave][4 * quad];
        if (t0 + 4 * quad + 3 < TT) {
            uint2 u;
            u.x = pk2(accPV[0] * rcpf_(rs.x), accPV[1] * rcpf_(rs.y));
            u.y = pk2(accPV[2] * rcpf_(rs.z), accPV[3] * rcpf_(rs.w));
            *(uint2*)&ah_p[(size_t)(b * 64 + h * 16 + col) * 152 + 8 * tt + 2 * quad] = u;
        }
    }
}

// ---------------------------------------------------------------------------
// k_out (MFMA): per (t-tile, n, t-quarter). x and out go through an LDS
// flat buffer so all global traffic is float4-coalesced. 41.6 KB LDS.
// ---------------------------------------------------------------------------
__global__ __launch_bounds__(256) void k_out(
        const float* __restrict__ x, const unsigned* __restrict__ W,
        float* __restrict__ out)
{
    const int tt = blockIdx.x, n = blockIdx.y, tq = blockIdx.z;
    if (tt == 18 && tq == 3) return;
    const int t0q = tt * 16 + tq * 4;
    const int tid = threadIdx.x;
    const unsigned* ah_p = W + WS_AH;
    const unsigned* awfrag = W + WS_AWF;
    const float* aoff = (const float*)(W + WS_AOFF);
    const float* scO  = (const float*)(W + WS_SCO);

    __shared__ unsigned fbuf[4 * 1024];    // 16 KB (ah A-frags)
    __shared__ float obuf[6400];           // 25.6 KB (x tile, then out tile)

    // stage x tile (64 o x 4 t x 25 v) via flat float4 (fully coalesced)
    for (int j = tid; j < 1600; j += 256) {
        const int o = j / 25, f4 = j - 25 * o;
        const float4 xv = *(const float4*)(x + (size_t)(n * 64 + o) * 7500 + t0q * 25 + f4 * 4);
        *(float4*)&obuf[o * 100 + f4 * 4] = xv;
    }
    // stage ah A-frags
    for (int i = tid; i < 1600; i += 256) {
        const int tp2 = i & 1, pc = (i >> 1) & 31, v = i >> 6;
        const int b = n * 25 + v;
        const size_t r0 = (size_t)(b * 64 + 2 * pc) * 152 + tt * 8 + tq * 2 + tp2;
        const unsigned A = ah_p[r0], Bv = ah_p[r0 + 152];
        const unsigned ue = (A & 0xFFFFu) | (Bv << 16);
        const unsigned uo = (A >> 16) | (Bv & 0xFFFF0000u);
        const int vt = v >> 4, cv = v & 15, ch = pc >> 4, qd = (pc >> 2) & 3, j2 = pc & 3;
        const int xi = (vt * 2 + ch) * 256 + (qd * 16 + (cv ^ qd)) * 4 + j2;
        const int tl = 2 * tp2;
        fbuf[tl * 1024 + ((xi + 12 * tl) & 1023)]             = ue;
        fbuf[(tl + 1) * 1024 + ((xi + 12 * (tl + 1)) & 1023)] = uo;
    }
    __syncthreads();

    const int wv = tid >> 6, lane = tid & 63, col = lane & 15, quad = lane >> 4;
    const int o = wv * 16 + col;
    const float4v zero4 = {0.f, 0.f, 0.f, 0.f};

    U8 awf0, awf1;
    { const uint4 u = *(const uint4*)&awfrag[(wv * 2 + 0) * 256 + lane * 4];
      awf0.w[0] = u.x; awf0.w[1] = u.y; awf0.w[2] = u.z; awf0.w[3] = u.w; }
    { const uint4 u = *(const uint4*)&awfrag[(wv * 2 + 1) * 256 + lane * 4];
      awf1.w[0] = u.x; awf1.w[1] = u.y; awf1.w[2] = u.z; awf1.w[3] = u.w; }
    const float aoff_l = aoff[o], sc_l = scO[o];

    for (int tl = 0; tl < 4; ++tl) {
        #pragma unroll
        for (int vt = 0; vt < 2; ++vt) {
            U8 a0, a1;
            { const int xb = (vt * 2 + 0) * 256 + (quad * 16 + (col ^ quad)) * 4;
              const uint4 u = *(const uint4*)&fbuf[tl * 1024 + ((xb + 12 * tl) & 1023)];
              a0.w[0] = u.x; a0.w[1] = u.y; a0.w[2] = u.z; a0.w[3] = u.w; }
            { const int xb = (vt * 2 + 1) * 256 + (quad * 16 + (col ^ quad)) * 4;
              const uint4 u = *(const uint4*)&fbuf[tl * 1024 + ((xb + 12 * tl) & 1023)];
              a1.w[0] = u.x; a1.w[1] = u.y; a1.w[2] = u.z; a1.w[3] = u.w; }
            float4v acc = __builtin_amdgcn_mfma_f32_16x16x32_bf16(a0.v, awf0.v, zero4, 0, 0, 0);
            acc = __builtin_amdgcn_mfma_f32_16x16x32_bf16(a1.v, awf1.v, acc, 0, 0, 0);
            #pragma unroll
            for (int r = 0; r < 4; ++r) {
                const int v = vt * 16 + 4 * quad + r;
                if (v < 25) {
                    const int oi = o * 100 + tl * 25 + v;
                    obuf[oi] = fmaxf(fmaf(obuf[oi], sc_l, acc[r] + aoff_l), 0.f);
                }
            }
        }
    }
    __syncthreads();

    // flush out tile via flat float4 (fully coalesced)
    for (int j = tid; j < 1600; j += 256) {
        const int o2 = j / 25, f4 = j - 25 * o2;
        *(float4*)(out + (size_t)(n * 64 + o2) * 7500 + t0q * 25 + f4 * 4) =
            *(const float4*)&obuf[o2 * 100 + f4 * 4];
    }
}

// ---------------------------------------------------------------------------
extern "C" void kernel_launch(void* const* d_in, const int* in_sizes, int n_in,
                              void* d_out, int out_size, void* d_ws, size_t ws_size,
                              hipStream_t stream)
{
    const float* x       = (const float*)d_in[0];
    const float* dbn_g   = (const float*)d_in[1];
    const float* dbn_b   = (const float*)d_in[2];
    const float* dbn_m   = (const float*)d_in[3];
    const float* dbn_v   = (const float*)d_in[4];
    const float* qkv_w   = (const float*)d_in[5];
    const float* qkv_b   = (const float*)d_in[6];
    const float* key_rel = (const float*)d_in[7];
    const float* attn_w  = (const float*)d_in[8];
    const float* attn_b  = (const float*)d_in[9];
    const float* bn_g    = (const float*)d_in[10];
    const float* bn_b    = (const float*)d_in[11];
    const float* bn_m    = (const float*)d_in[12];
    const float* bn_v    = (const float*)d_in[13];
    float* out = (float*)d_out;
    unsigned* W = (unsigned*)d_ws;

    k_pre<<<182, 256, 0, stream>>>(dbn_g, dbn_b, dbn_m, dbn_v, qkv_w, qkv_b,
                                   key_rel, attn_w, attn_b, bn_g, bn_b, bn_m,
                                   bn_v, W);
    k_qkv<<<dim3(19, 16), 512, 0, stream>>>(x, W);
    k_attn<<<dim3(1600, 2), 256, 0, stream>>>(W);
    k_out<<<dim3(19, 16, 4), 256, 0, stream>>>(x, W, out);
}

// Round 7
// 246.512 us; speedup vs baseline: 7.6150x; 1.0744x over previous
//
#include <hip/hip_runtime.h>
#include <hip/hip_bf16.h>
#include <cstddef>

// Problem constants
#define NN 16
#define CC 64
#define TT 300
#define VV 25
#define NHH 4
#define DKHH 16
#define BB (NN * VV)          // 400
#define EPS 1e-5f
#define LOG2E 1.4426950408889634f

// Workspace layout (u32 units)
#define WS_QK    0            // u32[400][64][300]  q|k bf16, paired along o (q pre-scaled 0.25*log2e)
#define WS_V     7680000      // u32[400][64][152]  v bf16, paired along t (t>=300 zero-filled)
#define WS_AH    11571200     // u32[400][64][152]  attnh bf16, paired along t
#define WS_REL   15462400     // u32[41][64][4] key_rel frags (slot = mtile+1, slot0 = zeros)
#define WS_AWF   15472896     // u32[4][2][64][4] attn_w B-frags (pre-scaled by bn scale)
#define WS_AOFF  15474944     // f32[64] fused attn_b+bn offset
#define WS_SCO   15475008     // f32[64] bn scale (for skip path)
#define WS_WFRAG 15475072     // u32[12][2][64][4] qkv_w B-frags (q pre-scaled 0.25*log2e)
#define WS_QB2   15481216     // f32[192] qkv_b (q pre-scaled)
#define WS_SCSH  15481408     // float2[1600] data_bn (sc, sh) per (c, v)

typedef __attribute__((ext_vector_type(8))) short short8;
typedef __attribute__((ext_vector_type(4))) float float4v;

union U8 { short8 v; unsigned int w[4]; };

// f32x2 -> packed bf16x2 (RNE). HW op if available, else manual.
__device__ __forceinline__ unsigned int pk2(float a, float b) {
#if __has_builtin(__builtin_amdgcn_cvt_pk_bf16_f32)
    typedef __attribute__((ext_vector_type(2))) __bf16 bf2;
    union { bf2 v; unsigned u; } c;
    c.v = __builtin_amdgcn_cvt_pk_bf16_f32(a, b);
    return c.u;
#else
    union { float f; unsigned u; } x, y;
    x.f = a; y.f = b;
    unsigned ua = x.u + 0x7FFFu + ((x.u >> 16) & 1u);
    unsigned ub = y.u + 0x7FFFu + ((y.u >> 16) & 1u);
    return (ua >> 16) | (ub & 0xFFFF0000u);
#endif
}

__device__ __forceinline__ float ex2(float x) {
#if __has_builtin(__builtin_amdgcn_exp2f)
    return __builtin_amdgcn_exp2f(x);
#else
    return exp2f(x);
#endif
}

__device__ __forceinline__ float rcpf_(float x) {
#if __has_builtin(__builtin_amdgcn_rcpf)
    return __builtin_amdgcn_rcpf(x);
#else
    return 1.f / x;
#endif
}

// ---------------------------------------------------------------------------
// k_pre: constant tables (shared wfrag/qb2 + scsh restored; per-v wv dropped).
// ---------------------------------------------------------------------------
__global__ __launch_bounds__(256) void k_pre(
    const float* __restrict__ dbn_g, const float* __restrict__ dbn_b,
    const float* __restrict__ dbn_m, const float* __restrict__ dbn_v,
    const float* __restrict__ qkv_w, const float* __restrict__ qkv_b,
    const float* __restrict__ key_rel,
    const float* __restrict__ attn_w, const float* __restrict__ attn_b,
    const float* __restrict__ bn_g, const float* __restrict__ bn_b,
    const float* __restrict__ bn_m, const float* __restrict__ bn_v,
    unsigned* __restrict__ W)
{
    const int jid = blockIdx.x * 256 + threadIdx.x;
    if (jid < 2624) {                      // relfrag: 41 slots x 64 lanes
        const int k = jid >> 6, lane = jid & 63, col = lane & 15, quad = lane >> 4;
        const int mt = k - 1, m = mt * 16 + col;
        const bool ok = (quad < 2) && (mt >= 0) && (m < 2 * TT - 1);
        unsigned w[4];
        #pragma unroll
        for (int j2 = 0; j2 < 4; ++j2) {
            const int c = quad * 8 + 2 * j2;
            const float v0 = ok ? key_rel[m * 16 + c] : 0.f;
            const float v1 = ok ? key_rel[m * 16 + c + 1] : 0.f;
            w[j2] = pk2(v0, v1);
        }
        *(uint4*)&W[WS_REL + k * 256 + lane * 4] = make_uint4(w[0], w[1], w[2], w[3]);
    } else if (jid < 3136) {               // awfrag: 4 otiles x 2 chalf x 64
        const int e = jid - 2624;
        const int ot = e >> 7, ch = (e >> 6) & 1, lane = e & 63;
        const int col = lane & 15, quad = lane >> 4;
        const int o = ot * 16 + col;
        const float sc = bn_g[o] * rsqrtf(bn_v[o] + EPS);
        unsigned w[4];
        #pragma unroll
        for (int j2 = 0; j2 < 4; ++j2) {
            const int c = ch * 32 + quad * 8 + 2 * j2;
            w[j2] = pk2(attn_w[o * 64 + c] * sc, attn_w[o * 64 + c + 1] * sc);
        }
        *(uint4*)&W[WS_AWF + (ot * 2 + ch) * 256 + lane * 4] = make_uint4(w[0], w[1], w[2], w[3]);
    } else if (jid < 3200) {               // aoff
        const int o = jid - 3136;
        const float sc = bn_g[o] * rsqrtf(bn_v[o] + EPS);
        ((float*)(W + WS_AOFF))[o] = attn_b[o] * sc + bn_b[o] - bn_m[o] * sc;
    } else if (jid < 3264) {               // scO
        const int o = jid - 3200;
        ((float*)(W + WS_SCO))[o] = bn_g[o] * rsqrtf(bn_v[o] + EPS);
    } else if (jid < 4800) {               // wfrag: 12 otiles x 2 chalf x 64
        const int e = jid - 3264;
        const int ot = e >> 7, ch = (e >> 6) & 1, lane = e & 63;
        const int col = lane & 15, quad = lane >> 4;
        const int o = ot * 16 + col;
        const float qs = (o < 64) ? 0.25f * LOG2E : 1.f;
        unsigned w[4];
        #pragma unroll
        for (int j2 = 0; j2 < 4; ++j2) {
            const int c = ch * 32 + quad * 8 + 2 * j2;
            w[j2] = pk2(qkv_w[o * 64 + c] * qs, qkv_w[o * 64 + c + 1] * qs);
        }
        *(uint4*)&W[WS_WFRAG + (ot * 2 + ch) * 256 + lane * 4] = make_uint4(w[0], w[1], w[2], w[3]);
    } else if (jid < 4992) {               // qb2
        const int o = jid - 4800;
        ((float*)(W + WS_QB2))[o] = qkv_b[o] * ((o < 64) ? 0.25f * LOG2E : 1.f);
    } else if (jid < 6592) {               // data_bn sc/sh per (c*25+v)
        const int e = jid - 4992;
        const float sc = dbn_g[e] * rsqrtf(dbn_v[e] + EPS);
        const float sh = dbn_b[e] - dbn_m[e] * sc;
        ((float2*)(W + WS_SCSH))[e] = make_float2(sc, sh);
    }
}

// ---------------------------------------------------------------------------
// k_qkv (MFMA): per (t-tile, n), 512 thr. float4 coalesced x loads, data_bn
// applied in staging (scsh fmaf); shared weight B-frags loaded ONCE per wave.
// ---------------------------------------------------------------------------
__global__ __launch_bounds__(512) void k_qkv(
        const float* __restrict__ x, unsigned* __restrict__ W)
{
    const int tt = blockIdx.x, n = blockIdx.y, t0 = tt * 16;
    const int tid = threadIdx.x;
    const float2* scsh = (const float2*)(W + WS_SCSH);
    const unsigned* wfrag = W + WS_WFRAG;
    const float* qb2 = (const float*)(W + WS_QB2);
    unsigned* qk_p = W + WS_QK;
    unsigned* v_p  = W + WS_V;

    __shared__ unsigned afrag[25 * 516];   // 51.6 KB

    // stage: 3200 jobs = 32 c-pairs x 100 float4 (contiguous flat = t*25+v)
    for (int i = tid; i < 3200; i += 512) {
        const int f4 = i % 100, cp = i / 100;
        const int c0 = cp * 2;
        float4 xa = make_float4(0.f, 0.f, 0.f, 0.f);
        float4 xb = make_float4(0.f, 0.f, 0.f, 0.f);
        if (tt < 18 || f4 < 75) {          // tail tile: only 300 floats valid
            const float* p = x + (size_t)(n * 64 + c0) * 7500 + tt * 400 + f4 * 4;
            xa = *(const float4*)p;
            xb = *(const float4*)(p + 7500);
        }
        const int ch = cp >> 4, qd = (cp >> 2) & 3, j2 = cp & 3;
        const float ea[4] = {xa.x, xa.y, xa.z, xa.w};
        const float eb[4] = {xb.x, xb.y, xb.z, xb.w};
        #pragma unroll
        for (int e = 0; e < 4; ++e) {
            const int flat = f4 * 4 + e;
            const int tl = (flat * 5243) >> 17;     // flat / 25
            const int v  = flat - 25 * tl;
            const float2 s0 = scsh[c0 * 25 + v];
            const float2 s1 = scsh[c0 * 25 + 25 + v];
            const float a0 = fmaf(ea[e], s0.x, s0.y);
            const float a1 = fmaf(eb[e], s1.x, s1.y);
            afrag[v * 516 + (ch * 64 + qd * 16 + tl) * 4 + j2] = pk2(a0, a1);
        }
    }
    __syncthreads();

    const int wvv = tid >> 6, lane = tid & 63, col = lane & 15, quad = lane >> 4;
    const int otg = wvv >> 1, vh = wvv & 1;
    const int vlo = 13 * vh, vhi = vh ? 25 : 13;
    const float4v zero4 = {0.f, 0.f, 0.f, 0.f};
    const bool tvalid = (t0 + 4 * quad + 3 < TT);

    U8 bf[3][2]; float qb_l[3];
    #pragma unroll
    for (int i = 0; i < 3; ++i) {
        const int ot = 3 * otg + i;
        #pragma unroll
        for (int ch = 0; ch < 2; ++ch) {
            const uint4 u = *(const uint4*)&wfrag[(ot * 2 + ch) * 256 + lane * 4];
            bf[i][ch].w[0] = u.x; bf[i][ch].w[1] = u.y; bf[i][ch].w[2] = u.z; bf[i][ch].w[3] = u.w;
        }
        qb_l[i] = qb2[ot * 16 + col];
    }

    for (int v = vlo; v < vhi; ++v) {
        const int b = n * 25 + v;
        U8 a0, a1;
        { const uint4 u = *(const uint4*)&afrag[v * 516 + lane * 4];
          a0.w[0] = u.x; a0.w[1] = u.y; a0.w[2] = u.z; a0.w[3] = u.w; }
        { const uint4 u = *(const uint4*)&afrag[v * 516 + 256 + lane * 4];
          a1.w[0] = u.x; a1.w[1] = u.y; a1.w[2] = u.z; a1.w[3] = u.w; }
        #pragma unroll
        for (int i = 0; i < 3; ++i) {
            const int ot = 3 * otg + i;
            float4v acc = __builtin_amdgcn_mfma_f32_16x16x32_bf16(a0.v, bf[i][0].v, zero4, 0, 0, 0);
            acc = __builtin_amdgcn_mfma_f32_16x16x32_bf16(a1.v, bf[i][1].v, acc, 0, 0, 0);
            float val[4];
            #pragma unroll
            for (int r = 0; r < 4; ++r) val[r] = acc[r] + qb_l[i];
            if (ot < 8) {                  // q|k: pair neighbor o lanes
                unsigned pk[4];
                #pragma unroll
                for (int r = 0; r < 4; ++r) {
                    const float p = __shfl_xor(val[r], 1);
                    pk[r] = pk2(val[r], p);
                }
                if (((col & 1) == 0) && tvalid) {
                    const int op = ot * 8 + (col >> 1);
                    *(uint4*)&qk_p[(size_t)(b * 64 + op) * TT + t0 + 4 * quad] =
                        make_uint4(pk[0], pk[1], pk[2], pk[3]);
                }
            } else {                       // v: pair along t; zero-fill t>=300
                const int d = (ot - 8) * 16 + col;
                uint2 u;
                if (tvalid) { u.x = pk2(val[0], val[1]); u.y = pk2(val[2], val[3]); }
                else        { u.x = 0u; u.y = 0u; }
                *(uint2*)&v_p[(size_t)(b * 64 + d) * 152 + 8 * tt + 2 * quad] = u;
            }
        }
    }
}

// ---------------------------------------------------------------------------
// k_attn: per (b, h, t-half). SHFL-FREE PV: V staged with s-permutation so
// the QK C-layout packs (pk2 of C rows) ARE the PV A-fragment. Per chunk:
// kbuf read -> 2 QK MFMA -> rel gather + exp2 -> pk2 -> PV MFMA.
// ---------------------------------------------------------------------------
__global__ __launch_bounds__(256) void k_attn(unsigned* __restrict__ W)
{
    const int bh = blockIdx.x;             // 0..1599
    const int half = blockIdx.y;           // t-range half
    const int b = bh >> 2, h = bh & 3;
    const int tid  = threadIdx.x;
    const int wave = tid >> 6, lane = tid & 63;
    const int col  = lane & 15, quad = lane >> 4;

    const unsigned* qk_p = W + WS_QK;
    const unsigned* v_p  = W + WS_V;
    unsigned* ah_p = W + WS_AH;
    const unsigned* relfrag = W + WS_REL;

    __shared__ unsigned kbuf[19 * 32 * 4];   // 9.7 KB
    __shared__ unsigned vbuf[10 * 64 * 4];   // 10.2 KB (s-permuted)
    __shared__ float relbuf[4][16 * 68];     // [t][m-ring+dup], 17.4 KB
    __shared__ float sbuf[4][16];

    for (int p = tid; p < 2432; p += 256) {
        const int c = p & 15, j2 = (p >> 4) & 3, qh = (p >> 6) & 1, st = p >> 7;
        kbuf[(st * 32 + qh * 16 + c) * 4 + j2] =
            qk_p[(size_t)(b * 64 + 32 + h * 8 + qh * 4 + j2) * TT + st * 16 + c];
    }
    // V staging with k<->s permutation: quad q of the PV A/B frag owns
    // s-pairs {2q, 2q+1, 8+2q, 8+2q+1} within each 32-s chunk.
    for (int p = tid; p < 640; p += 256) {
        const int tq = p % 40, d = p / 40;
        const int off = (tq * 4 <= 148) ? tq * 4 : 144;  // clamp (slots unused)
        const uint4 u = *(const uint4*)&v_p[(size_t)(b * 64 + h * 16 + d) * 152 + off];
        const int c = tq >> 2;
        const int l0 = (tq & 3) * 4;
        const unsigned uu[4] = {u.x, u.y, u.z, u.w};
        #pragma unroll
        for (int j = 0; j < 4; ++j) {
            const int local = l0 + j;
            const int q  = (local < 8) ? (local >> 1) : ((local - 8) >> 1);
            const int j2 = (local < 8) ? (local & 1) : (2 + (local & 1));
            vbuf[(c * 64 + q * 16 + d) * 4 + j2] = uu[j];
        }
    }
    __syncthreads();

    float* relw = &relbuf[wave][0];
    const float4v zero4 = {0.f, 0.f, 0.f, 0.f};

    const int ttlo = half ? 10 : 0;
    const int tthi = half ? 19 : 10;

    for (int tt = ttlo + wave; tt < tthi; tt += 4) {
        const int t0 = tt * 16;

        // ---- Q B-frag (cols = t) ----
        U8 qf;
        if (quad < 2) {
            int t = t0 + col; if (t > TT - 1) t = TT - 1;
            const size_t rb = (size_t)(b * 64 + h * 8 + quad * 4) * TT + t;
            qf.w[0] = qk_p[rb];
            qf.w[1] = qk_p[rb + TT];
            qf.w[2] = qk_p[rb + 2 * TT];
            qf.w[3] = qk_p[rb + 3 * TT];
        } else {
            qf.w[0] = qf.w[1] = qf.w[2] = qf.w[3] = 0u;
        }

        auto rel_ld = [&](int mt) -> uint4 {
            return *(const uint4*)&relfrag[(mt + 1) * 256 + lane * 4];
        };
        auto rel_do = [&](int mt, uint4 u) {
            U8 kr; kr.w[0] = u.x; kr.w[1] = u.y; kr.w[2] = u.z; kr.w[3] = u.w;
            const float4v rc = __builtin_amdgcn_mfma_f32_16x16x32_bf16(
                                   kr.v, qf.v, zero4, 0, 0, 0);
            const float4 s4 = make_float4(rc[0], rc[1], rc[2], rc[3]);
            *(float4*)&relw[col * 68 + ((mt & 3) * 16 + quad * 4)] = s4;
            if (((mt & 3) == 0) && (quad == 0))
                *(float4*)&relw[col * 68 + 64] = s4;
        };

        #pragma unroll
        for (int i = 0; i < 4; ++i) rel_do(17 - tt + i, rel_ld(17 - tt + i));
        uint4 ru0 = rel_ld(21 - tt), ru1 = rel_ld(22 - tt);

        float4v accPV = zero4;
        float sumA = 0.f;
        const int mbb = 4 * quad - t0 - col + (TT - 1);

        #pragma unroll 1
        for (int c = 0; c < 9; ++c) {       // chunks of 2 s-tiles: s 0..287
            U8 kf0, kf1;
            if (quad < 2) {
                const uint4 u0 = *(const uint4*)&kbuf[((2 * c) * 32 + quad * 16 + col) * 4];
                const uint4 u1 = *(const uint4*)&kbuf[((2 * c + 1) * 32 + quad * 16 + col) * 4];
                kf0.w[0] = u0.x; kf0.w[1] = u0.y; kf0.w[2] = u0.z; kf0.w[3] = u0.w;
                kf1.w[0] = u1.x; kf1.w[1] = u1.y; kf1.w[2] = u1.z; kf1.w[3] = u1.w;
            } else {
                kf0.w[0] = kf0.w[1] = kf0.w[2] = kf0.w[3] = 0u;
                kf1.w[0] = kf1.w[1] = kf1.w[2] = kf1.w[3] = 0u;
            }
            const float4v qk0 = __builtin_amdgcn_mfma_f32_16x16x32_bf16(kf0.v, qf.v, zero4, 0, 0, 0);
            const float4v qk1 = __builtin_amdgcn_mfma_f32_16x16x32_bf16(kf1.v, qf.v, zero4, 0, 0, 0);

            const int mb0 = 32 * c + mbb;
            const float* rp0 = &relw[col * 68 + (mb0 & 63)];
            const float* rp1 = &relw[col * 68 + ((mb0 + 16) & 63)];
            const float e0 = ex2(qk0[0] + rp0[0]);
            const float e1 = ex2(qk0[1] + rp0[1]);
            const float e2 = ex2(qk0[2] + rp0[2]);
            const float e3 = ex2(qk0[3] + rp0[3]);
            const float e4 = ex2(qk1[0] + rp1[0]);
            const float e5 = ex2(qk1[1] + rp1[1]);
            const float e6 = ex2(qk1[2] + rp1[2]);
            const float e7 = ex2(qk1[3] + rp1[3]);
            sumA += ((e0 + e1) + (e2 + e3)) + ((e4 + e5) + (e6 + e7));

            U8 pf;
            pf.w[0] = pk2(e0, e1);
            pf.w[1] = pk2(e2, e3);
            pf.w[2] = pk2(e4, e5);
            pf.w[3] = pk2(e6, e7);
            const short8 vf = *(const short8*)&vbuf[(c * 64 + lane) * 4];
            accPV = __builtin_amdgcn_mfma_f32_16x16x32_bf16(pf.v, vf, accPV, 0, 0, 0);

            rel_do(2 * c + 21 - tt, ru0);
            rel_do(2 * c + 22 - tt, ru1);
            if (c < 8) { ru0 = rel_ld(2 * c + 23 - tt); ru1 = rel_ld(2 * c + 24 - tt); }
        }

        // ---- tail chunk 9: stile 18 only (s 288..303; s>=300 masked) ----
        {
            U8 kf0;
            if (quad < 2) {
                const uint4 u0 = *(const uint4*)&kbuf[(18 * 32 + quad * 16 + col) * 4];
                kf0.w[0] = u0.x; kf0.w[1] = u0.y; kf0.w[2] = u0.z; kf0.w[3] = u0.w;
            } else {
                kf0.w[0] = kf0.w[1] = kf0.w[2] = kf0.w[3] = 0u;
            }
            const float4v qk0 = __builtin_amdgcn_mfma_f32_16x16x32_bf16(kf0.v, qf.v, zero4, 0, 0, 0);
            const int mb0 = 288 + mbb;
            const float* rp0 = &relw[col * 68 + (mb0 & 63)];
            float e0 = ex2(qk0[0] + rp0[0]);
            float e1 = ex2(qk0[1] + rp0[1]);
            float e2 = ex2(qk0[2] + rp0[2]);
            float e3 = ex2(qk0[3] + rp0[3]);
            if (quad == 3) { e0 = e1 = e2 = e3 = 0.f; }
            sumA += (e0 + e1) + (e2 + e3);
            U8 pf;
            pf.w[0] = pk2(e0, e1);
            pf.w[1] = pk2(e2, e3);
            pf.w[2] = 0u;
            pf.w[3] = 0u;
            const short8 vf = *(const short8*)&vbuf[(9 * 64 + lane) * 4];
            accPV = __builtin_amdgcn_mfma_f32_16x16x32_bf16(pf.v, vf, accPV, 0, 0, 0);
        }

        // ---- finalize: row sums, normalize (rcp), bf16 t-paired store ----
        sumA += __shfl_xor(sumA, 16, 64);
        sumA += __shfl_xor(sumA, 32, 64);
        if (lane < 16) sbuf[wave][lane] = sumA;
        const float4 rs = *(const float4*)&sbuf[wave][4 * quad];
        if (t0 + 4 * quad + 3 < TT) {
            uint2 u;
            u.x = pk2(accPV[0] * rcpf_(rs.x), accPV[1] * rcpf_(rs.y));
            u.y = pk2(accPV[2] * rcpf_(rs.z), accPV[3] * rcpf_(rs.w));
            *(uint2*)&ah_p[(size_t)(b * 64 + h * 16 + col) * 152 + 8 * tt + 2 * quad] = u;
        }
    }
}

// ---------------------------------------------------------------------------
// k_out (MFMA): per (t-tile, n, t-quarter), 512 thr (waves = otile x t-half).
// x and out through LDS flat buffers (float4-coalesced global traffic).
// ---------------------------------------------------------------------------
__global__ __launch_bounds__(512) void k_out(
        const float* __restrict__ x, const unsigned* __restrict__ W,
        float* __restrict__ out)
{
    const int tt = blockIdx.x, n = blockIdx.y, tq = blockIdx.z;
    if (tt == 18 && tq == 3) return;
    const int t0q = tt * 16 + tq * 4;
    const int tid = threadIdx.x;
    const unsigned* ah_p = W + WS_AH;
    const unsigned* awfrag = W + WS_AWF;
    const float* aoff = (const float*)(W + WS_AOFF);
    const float* scO  = (const float*)(W + WS_SCO);

    __shared__ unsigned fbuf[4 * 1024];    // 16 KB (ah A-frags)
    __shared__ float obuf[6400];           // 25.6 KB (x tile, then out tile)

    // stage x tile (64 o x 4 t x 25 v) via flat float4 (fully coalesced)
    for (int j = tid; j < 1600; j += 512) {
        const int o = j / 25, f4 = j - 25 * o;
        const float4 xv = *(const float4*)(x + (size_t)(n * 64 + o) * 7500 + t0q * 25 + f4 * 4);
        *(float4*)&obuf[o * 100 + f4 * 4] = xv;
    }
    // stage ah A-frags
    for (int i = tid; i < 1600; i += 512) {
        const int tp2 = i & 1, pc = (i >> 1) & 31, v = i >> 6;
        const int b = n * 25 + v;
        const size_t r0 = (size_t)(b * 64 + 2 * pc) * 152 + tt * 8 + tq * 2 + tp2;
        const unsigned A = ah_p[r0], Bv = ah_p[r0 + 152];
        const unsigned ue = (A & 0xFFFFu) | (Bv << 16);
        const unsigned uo = (A >> 16) | (Bv & 0xFFFF0000u);
        const int vt = v >> 4, cv = v & 15, ch = pc >> 4, qd = (pc >> 2) & 3, j2 = pc & 3;
        const int xi = (vt * 2 + ch) * 256 + (qd * 16 + (cv ^ qd)) * 4 + j2;
        const int tl = 2 * tp2;
        fbuf[tl * 1024 + ((xi + 12 * tl) & 1023)]             = ue;
        fbuf[(tl + 1) * 1024 + ((xi + 12 * (tl + 1)) & 1023)] = uo;
    }
    __syncthreads();

    const int wv = tid >> 6, lane = tid & 63, col = lane & 15, quad = lane >> 4;
    const int ow = wv & 3, th = wv >> 2;
    const int o = ow * 16 + col;
    const float4v zero4 = {0.f, 0.f, 0.f, 0.f};

    U8 awf0, awf1;
    { const uint4 u = *(const uint4*)&awfrag[(ow * 2 + 0) * 256 + lane * 4];
      awf0.w[0] = u.x; awf0.w[1] = u.y; awf0.w[2] = u.z; awf0.w[3] = u.w; }
    { const uint4 u = *(const uint4*)&awfrag[(ow * 2 + 1) * 256 + lane * 4];
      awf1.w[0] = u.x; awf1.w[1] = u.y; awf1.w[2] = u.z; awf1.w[3] = u.w; }
    const float aoff_l = aoff[o], sc_l = scO[o];

    for (int tl = 2 * th; tl < 2 * th + 2; ++tl) {
        #pragma unroll
        for (int vt = 0; vt < 2; ++vt) {
            U8 a0, a1;
            { const int xb = (vt * 2 + 0) * 256 + (quad * 16 + (col ^ quad)) * 4;
              const uint4 u = *(const uint4*)&fbuf[tl * 1024 + ((xb + 12 * tl) & 1023)];
              a0.w[0] = u.x; a0.w[1] = u.y; a0.w[2] = u.z; a0.w[3] = u.w; }
            { const int xb = (vt * 2 + 1) * 256 + (quad * 16 + (col ^ quad)) * 4;
              const uint4 u = *(const uint4*)&fbuf[tl * 1024 + ((xb + 12 * tl) & 1023)];
              a1.w[0] = u.x; a1.w[1] = u.y; a1.w[2] = u.z; a1.w[3] = u.w; }
            float4v acc = __builtin_amdgcn_mfma_f32_16x16x32_bf16(a0.v, awf0.v, zero4, 0, 0, 0);
            acc = __builtin_amdgcn_mfma_f32_16x16x32_bf16(a1.v, awf1.v, acc, 0, 0, 0);
            #pragma unroll
            for (int r = 0; r < 4; ++r) {
                const int v = vt * 16 + 4 * quad + r;
                if (v < 25) {
                    const int oi = o * 100 + tl * 25 + v;
                    obuf[oi] = fmaxf(fmaf(obuf[oi], sc_l, acc[r] + aoff_l), 0.f);
                }
            }
        }
    }
    __syncthreads();

    // flush out tile via flat float4 (fully coalesced)
    for (int j = tid; j < 1600; j += 512) {
        const int o2 = j / 25, f4 = j - 25 * o2;
        *(float4*)(out + (size_t)(n * 64 + o2) * 7500 + t0q * 25 + f4 * 4) =
            *(const float4*)&obuf[o2 * 100 + f4 * 4];
    }
}

// ---------------------------------------------------------------------------
extern "C" void kernel_launch(void* const* d_in, const int* in_sizes, int n_in,
                              void* d_out, int out_size, void* d_ws, size_t ws_size,
                              hipStream_t stream)
{
    const float* x       = (const float*)d_in[0];
    const float* dbn_g   = (const float*)d_in[1];
    const float* dbn_b   = (const float*)d_in[2];
    const float* dbn_m   = (const float*)d_in[3];
    const float* dbn_v   = (const float*)d_in[4];
    const float* qkv_w   = (const float*)d_in[5];
    const float* qkv_b   = (const float*)d_in[6];
    const float* key_rel = (const float*)d_in[7];
    const float* attn_w  = (const float*)d_in[8];
    const float* attn_b  = (const float*)d_in[9];
    const float* bn_g    = (const float*)d_in[10];
    const float* bn_b    = (const float*)d_in[11];
    const float* bn_m    = (const float*)d_in[12];
    const float* bn_v    = (const float*)d_in[13];
    float* out = (float*)d_out;
    unsigned* W = (unsigned*)d_ws;

    k_pre<<<26, 256, 0, stream>>>(dbn_g, dbn_b, dbn_m, dbn_v, qkv_w, qkv_b,
                                  key_rel, attn_w, attn_b, bn_g, bn_b, bn_m,
                                  bn_v, W);
    k_qkv<<<dim3(19, 16), 512, 0, stream>>>(x, W);
    k_attn<<<dim3(1600, 2), 256, 0, stream>>>(W);
    k_out<<<dim3(19, 16, 4), 512, 0, stream>>>(x, W, out);
}